// Round 4
// baseline (1089.691 us; speedup 1.0000x reference)
//
#include <hip/hip_runtime.h>
#include <math.h>

#define D_MODEL 1024
#define NUM_HEADS 16
#define DK 64
#define L_SEQ 2048
#define BATCH 2
#define LN_EPS 1e-5f
#define ENERGY_SCALE 0.1f

typedef __attribute__((ext_vector_type(8))) short short8;
typedef __attribute__((ext_vector_type(4))) float f32x4;

__device__ __forceinline__ float waveReduceSum(float v) {
#pragma unroll
    for (int off = 32; off > 0; off >>= 1) v += __shfl_xor(v, off, 64);
    return v;
}

__device__ __forceinline__ unsigned short f2bf(float f) {
    unsigned int u = __float_as_uint(f);
    u += 0x7fff + ((u >> 16) & 1);          // round-to-nearest-even
    return (unsigned short)(u >> 16);
}

// ---------------- fp32 -> bf16 convert, 6 matrices in one launch ----------------
__global__ __launch_bounds__(256) void cvt6(
    const float* s0, const float* s1, const float* s2,
    const float* s3, const float* s4, const float* s5,
    unsigned short* d0, unsigned short* d1, unsigned short* d2,
    unsigned short* d3, unsigned short* d4, unsigned short* d5,
    long long n0, long long n1, long long n2, long long n3, long long n4, long long n5)
{
    const float* s; unsigned short* d; long long n;
    switch (blockIdx.y) {
        case 0: s = s0; d = d0; n = n0; break;
        case 1: s = s1; d = d1; n = n1; break;
        case 2: s = s2; d = d2; n = n2; break;
        case 3: s = s3; d = d3; n = n3; break;
        case 4: s = s4; d = d4; n = n4; break;
        default: s = s5; d = d5; n = n5; break;
    }
    long long i = ((long long)blockIdx.x * 256 + threadIdx.x) * 4;
    if (i >= n) return;
    float4 v = *(const float4*)(s + i);
    ushort4 o;
    o.x = f2bf(v.x); o.y = f2bf(v.y); o.z = f2bf(v.z); o.w = f2bf(v.w);
    *(ushort4*)(d + i) = o;
}

// ---------------- bf16 MFMA GEMM, reg-pipelined staging ----------------
// C[M,N] = A[M,K] * B[N,K]^T (+bias); 128x128 tile, BK=64, 4 waves (2x2).
__global__ __launch_bounds__(256) void gemm_bf16(
    const unsigned short* __restrict__ A, const unsigned short* __restrict__ B,
    const float* __restrict__ bias, float* __restrict__ Cf, unsigned short* __restrict__ Ch,
    int N, int K, long long sA, long long sB, long long sC)
{
    A += (long long)blockIdx.z * sA;
    B += (long long)blockIdx.z * sB;
    __shared__ unsigned short As[128 * 72];
    __shared__ unsigned short Bs[128 * 72];
    const int tid = threadIdx.x;
    const int lane = tid & 63, w = tid >> 6;
    const int quad = lane >> 4, col = lane & 15;
    const int wm = w & 1, wn = w >> 1;
    const int row0 = blockIdx.y * 128, col0 = blockIdx.x * 128;

    f32x4 acc[4][4];
#pragma unroll
    for (int mt = 0; mt < 4; mt++)
#pragma unroll
        for (int nt = 0; nt < 4; nt++) acc[mt][nt] = (f32x4){0.f, 0.f, 0.f, 0.f};

    // prologue: stage k0=0
#pragma unroll
    for (int p = 0; p < 4; p++) {
        int u = tid + p * 256;
        int r = u >> 3, c = (u & 7) * 8;
        *(uint4*)(As + r * 72 + c) = *(const uint4*)(A + (long long)(row0 + r) * K + c);
        *(uint4*)(Bs + r * 72 + c) = *(const uint4*)(B + (long long)(col0 + r) * K + c);
    }
    __syncthreads();

    for (int k0 = 0; k0 < K; k0 += 64) {
        uint4 arn[4], brn[4];
        const bool more = (k0 + 64 < K);
        if (more) {
#pragma unroll
            for (int p = 0; p < 4; p++) {
                int u = tid + p * 256;
                int r = u >> 3, c = (u & 7) * 8;
                arn[p] = *(const uint4*)(A + (long long)(row0 + r) * K + k0 + 64 + c);
                brn[p] = *(const uint4*)(B + (long long)(col0 + r) * K + k0 + 64 + c);
            }
        }
#pragma unroll
        for (int kc = 0; kc < 2; kc++) {
            short8 af[4], bfr[4];
#pragma unroll
            for (int mt = 0; mt < 4; mt++)
                af[mt] = *(const short8*)(As + (wm * 64 + mt * 16 + col) * 72 + quad * 8 + kc * 32);
#pragma unroll
            for (int nt = 0; nt < 4; nt++)
                bfr[nt] = *(const short8*)(Bs + (wn * 64 + nt * 16 + col) * 72 + quad * 8 + kc * 32);
#pragma unroll
            for (int mt = 0; mt < 4; mt++)
#pragma unroll
                for (int nt = 0; nt < 4; nt++)
                    acc[mt][nt] = __builtin_amdgcn_mfma_f32_16x16x32_bf16(af[mt], bfr[nt], acc[mt][nt], 0, 0, 0);
        }
        __syncthreads();
        if (more) {
#pragma unroll
            for (int p = 0; p < 4; p++) {
                int u = tid + p * 256;
                int r = u >> 3, c = (u & 7) * 8;
                *(uint4*)(As + r * 72 + c) = arn[p];
                *(uint4*)(Bs + r * 72 + c) = brn[p];
            }
            __syncthreads();
        }
    }

#pragma unroll
    for (int mt = 0; mt < 4; mt++)
#pragma unroll
        for (int nt = 0; nt < 4; nt++)
#pragma unroll
            for (int reg = 0; reg < 4; reg++) {
                long long row = row0 + wm * 64 + mt * 16 + quad * 4 + reg;
                int c = col0 + wn * 64 + nt * 16 + col;
                float v = acc[mt][nt][reg];
                if (bias) v += bias[c];
                if (Cf) Cf[blockIdx.z * sC + row * N + c] = v;
                else    Ch[blockIdx.z * sC + row * N + c] = f2bf(v);
            }
}

// ---------------- fused projections, reg-pipelined ----------------
__global__ __launch_bounds__(256) void proj_gemm(
    const unsigned short* __restrict__ Xh,
    const unsigned short* __restrict__ wqh, const unsigned short* __restrict__ wkh,
    const unsigned short* __restrict__ wvh, const unsigned short* __restrict__ eph,
    const float* __restrict__ ep_b,
    unsigned short* __restrict__ Qh, unsigned short* __restrict__ Kh,
    unsigned short* __restrict__ Vf, float* __restrict__ EP)
{
    const unsigned short* B;
    switch (blockIdx.z) {
        case 0: B = wqh; break;
        case 1: B = wkh; break;
        case 2: B = wvh; break;
        default: B = eph; break;
    }
    __shared__ unsigned short As[128 * 72];
    __shared__ unsigned short Bs[128 * 72];
    const int tid = threadIdx.x;
    const int lane = tid & 63, w = tid >> 6;
    const int quad = lane >> 4, col = lane & 15;
    const int wm = w & 1, wn = w >> 1;
    const int row0 = blockIdx.y * 128, col0 = blockIdx.x * 128;
    const int K = D_MODEL, N = D_MODEL;

    f32x4 acc[4][4];
#pragma unroll
    for (int mt = 0; mt < 4; mt++)
#pragma unroll
        for (int nt = 0; nt < 4; nt++) acc[mt][nt] = (f32x4){0.f, 0.f, 0.f, 0.f};

#pragma unroll
    for (int p = 0; p < 4; p++) {
        int u = tid + p * 256;
        int r = u >> 3, c = (u & 7) * 8;
        *(uint4*)(As + r * 72 + c) = *(const uint4*)(Xh + (long long)(row0 + r) * K + c);
        *(uint4*)(Bs + r * 72 + c) = *(const uint4*)(B + (long long)(col0 + r) * K + c);
    }
    __syncthreads();

    for (int k0 = 0; k0 < K; k0 += 64) {
        uint4 arn[4], brn[4];
        const bool more = (k0 + 64 < K);
        if (more) {
#pragma unroll
            for (int p = 0; p < 4; p++) {
                int u = tid + p * 256;
                int r = u >> 3, c = (u & 7) * 8;
                arn[p] = *(const uint4*)(Xh + (long long)(row0 + r) * K + k0 + 64 + c);
                brn[p] = *(const uint4*)(B + (long long)(col0 + r) * K + k0 + 64 + c);
            }
        }
#pragma unroll
        for (int kc = 0; kc < 2; kc++) {
            short8 af[4], bfr[4];
#pragma unroll
            for (int mt = 0; mt < 4; mt++)
                af[mt] = *(const short8*)(As + (wm * 64 + mt * 16 + col) * 72 + quad * 8 + kc * 32);
#pragma unroll
            for (int nt = 0; nt < 4; nt++)
                bfr[nt] = *(const short8*)(Bs + (wn * 64 + nt * 16 + col) * 72 + quad * 8 + kc * 32);
#pragma unroll
            for (int mt = 0; mt < 4; mt++)
#pragma unroll
                for (int nt = 0; nt < 4; nt++)
                    acc[mt][nt] = __builtin_amdgcn_mfma_f32_16x16x32_bf16(af[mt], bfr[nt], acc[mt][nt], 0, 0, 0);
        }
        __syncthreads();
        if (more) {
#pragma unroll
            for (int p = 0; p < 4; p++) {
                int u = tid + p * 256;
                int r = u >> 3, c = (u & 7) * 8;
                *(uint4*)(As + r * 72 + c) = arn[p];
                *(uint4*)(Bs + r * 72 + c) = brn[p];
            }
            __syncthreads();
        }
    }

    unsigned short* Hout = (blockIdx.z == 0) ? Qh : (blockIdx.z == 1) ? Kh : Vf;
#pragma unroll
    for (int mt = 0; mt < 4; mt++)
#pragma unroll
        for (int nt = 0; nt < 4; nt++)
#pragma unroll
            for (int reg = 0; reg < 4; reg++) {
                long long row = row0 + wm * 64 + mt * 16 + quad * 4 + reg;
                int c = col0 + wn * 64 + nt * 16 + col;
                float v = acc[mt][nt][reg];
                if (blockIdx.z == 3) EP[row * N + c] = v + ep_b[c];
                else                 Hout[row * N + c] = f2bf(v);
            }
}

// ---------------- LayerNorm rows; fp32 out (outf) or bf16 out (outh) ----------------
__global__ __launch_bounds__(256) void ln_rows(
    const float* __restrict__ in, const float* __restrict__ res,
    const float* __restrict__ g, const float* __restrict__ bta,
    float* __restrict__ outf, unsigned short* __restrict__ outh)
{
    const long long row = blockIdx.x;
    const float* ip = in + row * D_MODEL;
    const float* rp = res ? res + row * D_MODEL : nullptr;
    const int tid = threadIdx.x;
    float vals[4];
    float s = 0.f, ss = 0.f;
#pragma unroll
    for (int j = 0; j < 4; j++) {
        int idx = tid + j * 256;
        float v = ip[idx];
        if (rp) v += rp[idx];
        vals[j] = v; s += v; ss += v * v;
    }
    __shared__ float sred[4], ssred[4];
    s = waveReduceSum(s); ss = waveReduceSum(ss);
    int wave = tid >> 6, lane = tid & 63;
    if (lane == 0) { sred[wave] = s; ssred[wave] = ss; }
    __syncthreads();
    float ts = sred[0] + sred[1] + sred[2] + sred[3];
    float tss = ssred[0] + ssred[1] + ssred[2] + ssred[3];
    float mu = ts * (1.f / D_MODEL);
    float var = tss * (1.f / D_MODEL) - mu * mu;
    float rs = rsqrtf(var + LN_EPS);
#pragma unroll
    for (int j = 0; j < 4; j++) {
        int idx = tid + j * 256;
        float o = (vals[j] - mu) * rs * g[idx] + bta[idx];
        if (outf) outf[row * D_MODEL + idx] = o;
        else      outh[row * D_MODEL + idx] = f2bf(o);
    }
}

// ---------------- V transpose: Vf[B,L,D] bf16 -> Vt[B,H,DK,L] bf16 ----------------
__global__ __launch_bounds__(256) void transpose_v(
    const unsigned short* __restrict__ V, unsigned short* __restrict__ Vt)
{
    const int m0 = blockIdx.x * 64, h = blockIdx.y, b = blockIdx.z;
    __shared__ unsigned int t[64][65];
    const int tid = threadIdx.x;
    {
        int r = tid >> 4, c4 = (tid & 15) * 4;
#pragma unroll
        for (int i = 0; i < 4; i++) {
            int row = r + i * 16;
            ushort4 v = *(const ushort4*)(V + ((long long)b * L_SEQ + m0 + row) * D_MODEL + h * DK + c4);
            t[row][c4] = v.x; t[row][c4 + 1] = v.y; t[row][c4 + 2] = v.z; t[row][c4 + 3] = v.w;
        }
    }
    __syncthreads();
    const int lane = tid & 63, wv = tid >> 6;
#pragma unroll
    for (int i = 0; i < 16; i++) {
        int d = wv * 16 + i;
        Vt[(((long long)(b * NUM_HEADS + h)) * DK + d) * L_SEQ + m0 + lane] = (unsigned short)t[lane][d];
    }
}

// ---------------- MFMA attention, reg-pipelined staging ----------------
// 64 q-rows per block, 4 waves (wave w owns rows w*16..w*16+15), m-tile 64.
__global__ __launch_bounds__(256) void attn_mfma(
    const unsigned short* __restrict__ Qh, const unsigned short* __restrict__ Kh,
    const unsigned short* __restrict__ Vt, const float* __restrict__ EB,
    float* __restrict__ attn_out, unsigned short* __restrict__ CTXh)
{
    __shared__ unsigned short Ks[64 * 72];
    __shared__ unsigned short Vts[64 * 72];
    __shared__ unsigned short Ps[4 * 16 * 72];

    const int tid = threadIdx.x;
    const int lane = tid & 63, w = tid >> 6;
    const int quad = lane >> 4, col = lane & 15;
    const int l0 = blockIdx.x * 64;
    const int h = blockIdx.y, b = blockIdx.z;

    // Q fragments direct from global (once; A-layout: row=col, k=kc*32+quad*8+j)
    short8 aq[2];
    {
        const unsigned short* qrow = Qh + ((long long)b * L_SEQ + l0 + w * 16 + col) * D_MODEL + h * DK;
        aq[0] = *(const short8*)(qrow + quad * 8);
        aq[1] = *(const short8*)(qrow + 32 + quad * 8);
    }

    const float* ebp = EB + ((long long)b * L_SEQ + l0 + w * 16 + quad * 4) * L_SEQ + col;
    const unsigned short* kbase = Kh + ((long long)b * L_SEQ) * D_MODEL + h * DK;
    const unsigned short* vbase = Vt + ((long long)(b * NUM_HEADS + h)) * DK * L_SEQ;

    const int sr = tid >> 2, sc0 = (tid & 3) * 16;

    float rowM[4] = {-1e30f, -1e30f, -1e30f, -1e30f};
    float rowS[4] = {0.f, 0.f, 0.f, 0.f};

    // ================= sweep 1: row max & sum =================
    float ebc[4][4];
    {   // prologue: stage tile 0
        *(uint4*)(Ks + sr * 72 + sc0)     = *(const uint4*)(kbase + (long long)sr * D_MODEL + sc0);
        *(uint4*)(Ks + sr * 72 + sc0 + 8) = *(const uint4*)(kbase + (long long)sr * D_MODEL + sc0 + 8);
#pragma unroll
        for (int nt = 0; nt < 4; nt++)
#pragma unroll
            for (int reg = 0; reg < 4; reg++)
                ebc[nt][reg] = ebp[(long long)reg * L_SEQ + nt * 16];
    }
    __syncthreads();

    for (int t = 0; t < 32; t++) {
        const int m1 = (t + 1) * 64;
        uint4 ka, kb;
        float ebn[4][4];
        if (t < 31) {   // issue next-tile loads (in flight behind compute)
            ka = *(const uint4*)(kbase + (long long)(m1 + sr) * D_MODEL + sc0);
            kb = *(const uint4*)(kbase + (long long)(m1 + sr) * D_MODEL + sc0 + 8);
#pragma unroll
            for (int nt = 0; nt < 4; nt++)
#pragma unroll
                for (int reg = 0; reg < 4; reg++)
                    ebn[nt][reg] = ebp[(long long)reg * L_SEQ + m1 + nt * 16];
        }

        f32x4 acc[4];
#pragma unroll
        for (int nt = 0; nt < 4; nt++) acc[nt] = (f32x4){0.f, 0.f, 0.f, 0.f};
#pragma unroll
        for (int nt = 0; nt < 4; nt++)
#pragma unroll
            for (int kc = 0; kc < 2; kc++) {
                short8 bk = *(const short8*)(Ks + (nt * 16 + col) * 72 + quad * 8 + kc * 32);
                acc[nt] = __builtin_amdgcn_mfma_f32_16x16x32_bf16(aq[kc], bk, acc[nt], 0, 0, 0);
            }

        float sv[4][4];
#pragma unroll
        for (int nt = 0; nt < 4; nt++)
#pragma unroll
            for (int reg = 0; reg < 4; reg++)
                sv[nt][reg] = acc[nt][reg] * 0.125f + ENERGY_SCALE * ebc[nt][reg];

#pragma unroll
        for (int reg = 0; reg < 4; reg++) {
            float tm = fmaxf(fmaxf(sv[0][reg], sv[1][reg]), fmaxf(sv[2][reg], sv[3][reg]));
#pragma unroll
            for (int off = 8; off > 0; off >>= 1) tm = fmaxf(tm, __shfl_xor(tm, off, 64));
            float nm = fmaxf(rowM[reg], tm);
            float tsum = __expf(sv[0][reg] - nm) + __expf(sv[1][reg] - nm) +
                         __expf(sv[2][reg] - nm) + __expf(sv[3][reg] - nm);
#pragma unroll
            for (int off = 8; off > 0; off >>= 1) tsum += __shfl_xor(tsum, off, 64);
            rowS[reg] = rowS[reg] * __expf(rowM[reg] - nm) + tsum;
            rowM[reg] = nm;
        }

        __syncthreads();
        if (t < 31) {
            *(uint4*)(Ks + sr * 72 + sc0)     = ka;
            *(uint4*)(Ks + sr * 72 + sc0 + 8) = kb;
            __syncthreads();
#pragma unroll
            for (int nt = 0; nt < 4; nt++)
#pragma unroll
                for (int reg = 0; reg < 4; reg++)
                    ebc[nt][reg] = ebn[nt][reg];
        }
    }

    float invS[4];
#pragma unroll
    for (int reg = 0; reg < 4; reg++) invS[reg] = 1.f / rowS[reg];

    // ================= sweep 2: write attn, ctx = P V =================
    f32x4 ctx[4];
#pragma unroll
    for (int nt = 0; nt < 4; nt++) ctx[nt] = (f32x4){0.f, 0.f, 0.f, 0.f};

    unsigned short* Psw = Ps + w * 16 * 72;
    float* aob = attn_out + (((long long)(b * NUM_HEADS + h)) * L_SEQ + l0 + w * 16 + quad * 4) * L_SEQ + col;

    {   // prologue: stage tile 0 (K + V)
        *(uint4*)(Ks + sr * 72 + sc0)      = *(const uint4*)(kbase + (long long)sr * D_MODEL + sc0);
        *(uint4*)(Ks + sr * 72 + sc0 + 8)  = *(const uint4*)(kbase + (long long)sr * D_MODEL + sc0 + 8);
        *(uint4*)(Vts + sr * 72 + sc0)     = *(const uint4*)(vbase + (long long)sr * L_SEQ + sc0);
        *(uint4*)(Vts + sr * 72 + sc0 + 8) = *(const uint4*)(vbase + (long long)sr * L_SEQ + sc0 + 8);
#pragma unroll
        for (int nt = 0; nt < 4; nt++)
#pragma unroll
            for (int reg = 0; reg < 4; reg++)
                ebc[nt][reg] = ebp[(long long)reg * L_SEQ + nt * 16];
    }
    __syncthreads();

    for (int t = 0; t < 32; t++) {
        const int m0 = t * 64, m1 = m0 + 64;
        uint4 ka, kb, va, vb;
        float ebn[4][4];
        if (t < 31) {
            ka = *(const uint4*)(kbase + (long long)(m1 + sr) * D_MODEL + sc0);
            kb = *(const uint4*)(kbase + (long long)(m1 + sr) * D_MODEL + sc0 + 8);
            va = *(const uint4*)(vbase + (long long)sr * L_SEQ + m1 + sc0);
            vb = *(const uint4*)(vbase + (long long)sr * L_SEQ + m1 + sc0 + 8);
#pragma unroll
            for (int nt = 0; nt < 4; nt++)
#pragma unroll
                for (int reg = 0; reg < 4; reg++)
                    ebn[nt][reg] = ebp[(long long)reg * L_SEQ + m1 + nt * 16];
        }

        f32x4 acc[4];
#pragma unroll
        for (int nt = 0; nt < 4; nt++) acc[nt] = (f32x4){0.f, 0.f, 0.f, 0.f};
#pragma unroll
        for (int nt = 0; nt < 4; nt++)
#pragma unroll
            for (int kc = 0; kc < 2; kc++) {
                short8 bk = *(const short8*)(Ks + (nt * 16 + col) * 72 + quad * 8 + kc * 32);
                acc[nt] = __builtin_amdgcn_mfma_f32_16x16x32_bf16(aq[kc], bk, acc[nt], 0, 0, 0);
            }

#pragma unroll
        for (int nt = 0; nt < 4; nt++)
#pragma unroll
            for (int reg = 0; reg < 4; reg++) {
                float s = acc[nt][reg] * 0.125f + ENERGY_SCALE * ebc[nt][reg];
                float p = __expf(s - rowM[reg]) * invS[reg];
                aob[(long long)reg * L_SEQ + m0 + nt * 16] = p;
                Psw[(quad * 4 + reg) * 72 + nt * 16 + col] = f2bf(p);
            }

        short8 ap[2];
#pragma unroll
        for (int kc = 0; kc < 2; kc++)
            ap[kc] = *(const short8*)(Psw + col * 72 + quad * 8 + kc * 32);
#pragma unroll
        for (int nt = 0; nt < 4; nt++)
#pragma unroll
            for (int kc = 0; kc < 2; kc++) {
                short8 bv = *(const short8*)(Vts + (nt * 16 + col) * 72 + quad * 8 + kc * 32);
                ctx[nt] = __builtin_amdgcn_mfma_f32_16x16x32_bf16(ap[kc], bv, ctx[nt], 0, 0, 0);
            }

        __syncthreads();
        if (t < 31) {
            *(uint4*)(Ks + sr * 72 + sc0)      = ka;
            *(uint4*)(Ks + sr * 72 + sc0 + 8)  = kb;
            *(uint4*)(Vts + sr * 72 + sc0)     = va;
            *(uint4*)(Vts + sr * 72 + sc0 + 8) = vb;
            __syncthreads();
#pragma unroll
            for (int nt = 0; nt < 4; nt++)
#pragma unroll
                for (int reg = 0; reg < 4; reg++)
                    ebc[nt][reg] = ebn[nt][reg];
        }
    }

#pragma unroll
    for (int nt = 0; nt < 4; nt++)
#pragma unroll
        for (int reg = 0; reg < 4; reg++)
            CTXh[((long long)b * L_SEQ + l0 + w * 16 + quad * 4 + reg) * D_MODEL + h * DK + nt * 16 + col] =
                f2bf(ctx[nt][reg]);
}

extern "C" void kernel_launch(void* const* d_in, const int* in_sizes, int n_in,
                              void* d_out, int out_size, void* d_ws, size_t ws_size,
                              hipStream_t stream) {
    const float* x    = (const float*)d_in[0];
    const float* wq   = (const float*)d_in[1];
    const float* wk   = (const float*)d_in[2];
    const float* wv   = (const float*)d_in[3];
    const float* wo_w = (const float*)d_in[4];
    const float* wo_b = (const float*)d_in[5];
    const float* ep_w = (const float*)d_in[6];
    const float* ep_b = (const float*)d_in[7];
    const float* en_g = (const float*)d_in[8];
    const float* en_b = (const float*)d_in[9];
    const float* ln_g = (const float*)d_in[10];
    const float* ln_b = (const float*)d_in[11];

    float* out_final = (float*)d_out;
    float* attn_out  = out_final + (long long)BATCH * L_SEQ * D_MODEL;

    const long long MD = (long long)BATCH * L_SEQ * D_MODEL;   // 4,194,304
    const long long WN = (long long)D_MODEL * D_MODEL;         // 1,048,576

    float* EB = (float*)d_ws;                                  // [B,L,L] fp32
    float* EP = EB + (long long)BATCH * L_SEQ * L_SEQ;         // MD fp32 (also OUT)
    unsigned short* Xh   = (unsigned short*)(EP + MD);
    unsigned short* Qh   = Xh + MD;
    unsigned short* Kh   = Qh + MD;
    unsigned short* Vf   = Kh + MD;
    unsigned short* Vt   = Vf + MD;
    unsigned short* EFh  = Vt + MD;
    unsigned short* CTXh = EFh + MD;
    unsigned short* wqh  = CTXh + MD;
    unsigned short* wkh  = wqh + WN;
    unsigned short* wvh  = wkh + WN;
    unsigned short* eph  = wvh + WN;
    unsigned short* woh  = eph + WN;
    float* OUT = EP;                                           // EP dead after ln

    const int M = BATCH * L_SEQ;                               // 4096
    dim3 blk(256);

    cvt6<<<dim3((unsigned)(MD / 1024), 6), blk, 0, stream>>>(
        x, wq, wk, wv, ep_w, wo_w, Xh, wqh, wkh, wvh, eph, woh,
        MD, WN, WN, WN, WN, WN);

    proj_gemm<<<dim3(D_MODEL / 128, M / 128, 4), blk, 0, stream>>>(
        Xh, wqh, wkh, wvh, eph, ep_b, Qh, Kh, Vf, EP);

    ln_rows<<<dim3(M), blk, 0, stream>>>(EP, nullptr, en_g, en_b, nullptr, EFh);

    gemm_bf16<<<dim3(L_SEQ / 128, L_SEQ / 128, BATCH), blk, 0, stream>>>(
        EFh, EFh, nullptr, EB, nullptr, L_SEQ, D_MODEL,
        (long long)L_SEQ * D_MODEL, (long long)L_SEQ * D_MODEL,
        (long long)L_SEQ * L_SEQ);

    transpose_v<<<dim3(L_SEQ / 64, NUM_HEADS, BATCH), blk, 0, stream>>>(Vf, Vt);

    attn_mfma<<<dim3(L_SEQ / 64, NUM_HEADS, BATCH), blk, 0, stream>>>(
        Qh, Kh, Vt, EB, attn_out, CTXh);

    gemm_bf16<<<dim3(D_MODEL / 128, M / 128, 1), blk, 0, stream>>>(
        CTXh, woh, wo_b, OUT, nullptr, D_MODEL, D_MODEL, 0, 0, 0);

    ln_rows<<<dim3(M), blk, 0, stream>>>(OUT, x, ln_g, ln_b, out_final, nullptr);
}

// Round 5
// 905.300 us; speedup vs baseline: 1.2037x; 1.2037x over previous
//
#include <hip/hip_runtime.h>
#include <math.h>

#define D_MODEL 1024
#define NUM_HEADS 16
#define DK 64
#define L_SEQ 2048
#define BATCH 2
#define LN_EPS 1e-5f
#define ENERGY_SCALE 0.1f

typedef __attribute__((ext_vector_type(8))) short short8;
typedef __attribute__((ext_vector_type(4))) float f32x4;

__device__ __forceinline__ float waveReduceSum(float v) {
#pragma unroll
    for (int off = 32; off > 0; off >>= 1) v += __shfl_xor(v, off, 64);
    return v;
}

__device__ __forceinline__ unsigned short f2bf(float f) {
    unsigned int u = __float_as_uint(f);
    u += 0x7fff + ((u >> 16) & 1);          // round-to-nearest-even
    return (unsigned short)(u >> 16);
}

// ---------------- fp32 -> bf16 convert, 6 matrices in one launch ----------------
__global__ __launch_bounds__(256) void cvt6(
    const float* s0, const float* s1, const float* s2,
    const float* s3, const float* s4, const float* s5,
    unsigned short* d0, unsigned short* d1, unsigned short* d2,
    unsigned short* d3, unsigned short* d4, unsigned short* d5,
    long long n0, long long n1, long long n2, long long n3, long long n4, long long n5)
{
    const float* s; unsigned short* d; long long n;
    switch (blockIdx.y) {
        case 0: s = s0; d = d0; n = n0; break;
        case 1: s = s1; d = d1; n = n1; break;
        case 2: s = s2; d = d2; n = n2; break;
        case 3: s = s3; d = d3; n = n3; break;
        case 4: s = s4; d = d4; n = n4; break;
        default: s = s5; d = d5; n = n5; break;
    }
    long long i = ((long long)blockIdx.x * 256 + threadIdx.x) * 4;
    if (i >= n) return;
    float4 v = *(const float4*)(s + i);
    ushort4 o;
    o.x = f2bf(v.x); o.y = f2bf(v.y); o.z = f2bf(v.z); o.w = f2bf(v.w);
    *(ushort4*)(d + i) = o;
}

// ---------------- bf16 MFMA GEMM (round-3 verified version) ----------------
// C[M,N] = A[M,K] * B[N,K]^T (+bias); 128x128 tile, BK=64, 4 waves (2x2).
__global__ __launch_bounds__(256) void gemm_bf16(
    const unsigned short* __restrict__ A, const unsigned short* __restrict__ B,
    const float* __restrict__ bias, float* __restrict__ Cf, unsigned short* __restrict__ Ch,
    int N, int K, long long sA, long long sB, long long sC)
{
    A += (long long)blockIdx.z * sA;
    B += (long long)blockIdx.z * sB;
    __shared__ unsigned short As[128 * 72];
    __shared__ unsigned short Bs[128 * 72];
    const int tid = threadIdx.x;
    const int lane = tid & 63, w = tid >> 6;
    const int quad = lane >> 4, col = lane & 15;
    const int wm = w & 1, wn = w >> 1;
    const int row0 = blockIdx.y * 128, col0 = blockIdx.x * 128;

    f32x4 acc[4][4];
#pragma unroll
    for (int mt = 0; mt < 4; mt++)
#pragma unroll
        for (int nt = 0; nt < 4; nt++) acc[mt][nt] = (f32x4){0.f, 0.f, 0.f, 0.f};

    for (int k0 = 0; k0 < K; k0 += 64) {
        __syncthreads();
#pragma unroll
        for (int p = 0; p < 4; p++) {
            int u = tid + p * 256;
            int r = u >> 3;
            int c = (u & 7) * 8;
            *(uint4*)(As + r * 72 + c) = *(const uint4*)(A + (long long)(row0 + r) * K + k0 + c);
            *(uint4*)(Bs + r * 72 + c) = *(const uint4*)(B + (long long)(col0 + r) * K + k0 + c);
        }
        __syncthreads();
#pragma unroll
        for (int kc = 0; kc < 2; kc++) {
            short8 af[4], bfr[4];
#pragma unroll
            for (int mt = 0; mt < 4; mt++)
                af[mt] = *(const short8*)(As + (wm * 64 + mt * 16 + col) * 72 + quad * 8 + kc * 32);
#pragma unroll
            for (int nt = 0; nt < 4; nt++)
                bfr[nt] = *(const short8*)(Bs + (wn * 64 + nt * 16 + col) * 72 + quad * 8 + kc * 32);
#pragma unroll
            for (int mt = 0; mt < 4; mt++)
#pragma unroll
                for (int nt = 0; nt < 4; nt++)
                    acc[mt][nt] = __builtin_amdgcn_mfma_f32_16x16x32_bf16(af[mt], bfr[nt], acc[mt][nt], 0, 0, 0);
        }
    }

#pragma unroll
    for (int mt = 0; mt < 4; mt++)
#pragma unroll
        for (int nt = 0; nt < 4; nt++)
#pragma unroll
            for (int reg = 0; reg < 4; reg++) {
                long long row = row0 + wm * 64 + mt * 16 + quad * 4 + reg;
                int c = col0 + wn * 64 + nt * 16 + col;
                float v = acc[mt][nt][reg];
                if (bias) v += bias[c];
                if (Cf) Cf[blockIdx.z * sC + row * N + c] = v;
                else    Ch[blockIdx.z * sC + row * N + c] = f2bf(v);
            }
}

// ---------------- fused projections (round-3 verified version) ----------------
__global__ __launch_bounds__(256) void proj_gemm(
    const unsigned short* __restrict__ Xh,
    const unsigned short* __restrict__ wqh, const unsigned short* __restrict__ wkh,
    const unsigned short* __restrict__ wvh, const unsigned short* __restrict__ eph,
    const float* __restrict__ ep_b,
    unsigned short* __restrict__ Qh, unsigned short* __restrict__ Kh,
    unsigned short* __restrict__ Vf, float* __restrict__ EP)
{
    const unsigned short* B;
    switch (blockIdx.z) {
        case 0: B = wqh; break;
        case 1: B = wkh; break;
        case 2: B = wvh; break;
        default: B = eph; break;
    }
    __shared__ unsigned short As[128 * 72];
    __shared__ unsigned short Bs[128 * 72];
    const int tid = threadIdx.x;
    const int lane = tid & 63, w = tid >> 6;
    const int quad = lane >> 4, col = lane & 15;
    const int wm = w & 1, wn = w >> 1;
    const int row0 = blockIdx.y * 128, col0 = blockIdx.x * 128;
    const int K = D_MODEL, N = D_MODEL;

    f32x4 acc[4][4];
#pragma unroll
    for (int mt = 0; mt < 4; mt++)
#pragma unroll
        for (int nt = 0; nt < 4; nt++) acc[mt][nt] = (f32x4){0.f, 0.f, 0.f, 0.f};

    for (int k0 = 0; k0 < K; k0 += 64) {
        __syncthreads();
#pragma unroll
        for (int p = 0; p < 4; p++) {
            int u = tid + p * 256;
            int r = u >> 3;
            int c = (u & 7) * 8;
            *(uint4*)(As + r * 72 + c) = *(const uint4*)(Xh + (long long)(row0 + r) * K + k0 + c);
            *(uint4*)(Bs + r * 72 + c) = *(const uint4*)(B + (long long)(col0 + r) * K + k0 + c);
        }
        __syncthreads();
#pragma unroll
        for (int kc = 0; kc < 2; kc++) {
            short8 af[4], bfr[4];
#pragma unroll
            for (int mt = 0; mt < 4; mt++)
                af[mt] = *(const short8*)(As + (wm * 64 + mt * 16 + col) * 72 + quad * 8 + kc * 32);
#pragma unroll
            for (int nt = 0; nt < 4; nt++)
                bfr[nt] = *(const short8*)(Bs + (wn * 64 + nt * 16 + col) * 72 + quad * 8 + kc * 32);
#pragma unroll
            for (int mt = 0; mt < 4; mt++)
#pragma unroll
                for (int nt = 0; nt < 4; nt++)
                    acc[mt][nt] = __builtin_amdgcn_mfma_f32_16x16x32_bf16(af[mt], bfr[nt], acc[mt][nt], 0, 0, 0);
        }
    }

    unsigned short* Hout = (blockIdx.z == 0) ? Qh : (blockIdx.z == 1) ? Kh : Vf;
#pragma unroll
    for (int mt = 0; mt < 4; mt++)
#pragma unroll
        for (int nt = 0; nt < 4; nt++)
#pragma unroll
            for (int reg = 0; reg < 4; reg++) {
                long long row = row0 + wm * 64 + mt * 16 + quad * 4 + reg;
                int c = col0 + wn * 64 + nt * 16 + col;
                float v = acc[mt][nt][reg];
                if (blockIdx.z == 3) EP[row * N + c] = v + ep_b[c];
                else                 Hout[row * N + c] = f2bf(v);
            }
}

// ---------------- LayerNorm rows; fp32 out (outf) or bf16 out (outh) ----------------
__global__ __launch_bounds__(256) void ln_rows(
    const float* __restrict__ in, const float* __restrict__ res,
    const float* __restrict__ g, const float* __restrict__ bta,
    float* __restrict__ outf, unsigned short* __restrict__ outh)
{
    const long long row = blockIdx.x;
    const float* ip = in + row * D_MODEL;
    const float* rp = res ? res + row * D_MODEL : nullptr;
    const int tid = threadIdx.x;
    float vals[4];
    float s = 0.f, ss = 0.f;
#pragma unroll
    for (int j = 0; j < 4; j++) {
        int idx = tid + j * 256;
        float v = ip[idx];
        if (rp) v += rp[idx];
        vals[j] = v; s += v; ss += v * v;
    }
    __shared__ float sred[4], ssred[4];
    s = waveReduceSum(s); ss = waveReduceSum(ss);
    int wave = tid >> 6, lane = tid & 63;
    if (lane == 0) { sred[wave] = s; ssred[wave] = ss; }
    __syncthreads();
    float ts = sred[0] + sred[1] + sred[2] + sred[3];
    float tss = ssred[0] + ssred[1] + ssred[2] + ssred[3];
    float mu = ts * (1.f / D_MODEL);
    float var = tss * (1.f / D_MODEL) - mu * mu;
    float rs = rsqrtf(var + LN_EPS);
#pragma unroll
    for (int j = 0; j < 4; j++) {
        int idx = tid + j * 256;
        float o = (vals[j] - mu) * rs * g[idx] + bta[idx];
        if (outf) outf[row * D_MODEL + idx] = o;
        else      outh[row * D_MODEL + idx] = f2bf(o);
    }
}

// ---------------- V transpose: Vf[B,L,D] bf16 -> Vt[B,H,DK,L] bf16 ----------------
__global__ __launch_bounds__(256) void transpose_v(
    const unsigned short* __restrict__ V, unsigned short* __restrict__ Vt)
{
    const int m0 = blockIdx.x * 64, h = blockIdx.y, b = blockIdx.z;
    __shared__ unsigned int t[64][65];
    const int tid = threadIdx.x;
    {
        int r = tid >> 4, c4 = (tid & 15) * 4;
#pragma unroll
        for (int i = 0; i < 4; i++) {
            int row = r + i * 16;
            ushort4 v = *(const ushort4*)(V + ((long long)b * L_SEQ + m0 + row) * D_MODEL + h * DK + c4);
            t[row][c4] = v.x; t[row][c4 + 1] = v.y; t[row][c4 + 2] = v.z; t[row][c4 + 3] = v.w;
        }
    }
    __syncthreads();
    const int lane = tid & 63, wv = tid >> 6;
#pragma unroll
    for (int i = 0; i < 16; i++) {
        int d = wv * 16 + i;
        Vt[(((long long)(b * NUM_HEADS + h)) * DK + d) * L_SEQ + m0 + lane] = (unsigned short)t[lane][d];
    }
}

// ---------------- MFMA attention: single-barrier ping-pong staging ----------------
// 64 q-rows per block, 4 waves, m-tile 64. LDS: K0|K1|V0|V1|Ps = 5*9216 B = 45 KB.
// Sweep 1 ping-pongs K between K0/K1; sweep 2 ping-pongs (K,V) pairs.
// Per tile: issue next-tile global loads -> compute on current buffer ->
// ds_write landed data into other buffer -> ONE __syncthreads().
__global__ __launch_bounds__(256) void attn_mfma(
    const unsigned short* __restrict__ Qh, const unsigned short* __restrict__ Kh,
    const unsigned short* __restrict__ Vt, const float* __restrict__ EB,
    float* __restrict__ attn_out, unsigned short* __restrict__ CTXh)
{
    __shared__ unsigned short smem[5 * 64 * 72];
    unsigned short* K0 = smem;
    unsigned short* K1 = smem + 4608;
    unsigned short* V0 = smem + 2 * 4608;
    unsigned short* V1 = smem + 3 * 4608;
    unsigned short* Ps = smem + 4 * 4608;

    const int tid = threadIdx.x;
    const int lane = tid & 63, w = tid >> 6;
    const int quad = lane >> 4, col = lane & 15;
    const int l0 = blockIdx.x * 64;
    const int h = blockIdx.y, b = blockIdx.z;

    // Q fragments direct from global (A-layout: row=col, k=kc*32+quad*8+j)
    short8 aq[2];
    {
        const unsigned short* qrow = Qh + ((long long)b * L_SEQ + l0 + w * 16 + col) * D_MODEL + h * DK;
        aq[0] = *(const short8*)(qrow + quad * 8);
        aq[1] = *(const short8*)(qrow + 32 + quad * 8);
    }

    const float* ebp = EB + ((long long)b * L_SEQ + l0 + w * 16 + quad * 4) * L_SEQ + col;
    const unsigned short* kbase = Kh + ((long long)b * L_SEQ) * D_MODEL + h * DK;
    const unsigned short* vbase = Vt + ((long long)(b * NUM_HEADS + h)) * DK * L_SEQ;

    const int sr = tid >> 2, sc0 = (tid & 3) * 16;

    float rowM[4] = {-1e30f, -1e30f, -1e30f, -1e30f};
    float rowS[4] = {0.f, 0.f, 0.f, 0.f};
    float ebc[4][4];

    // ================= sweep 1: row max & sum (K ping-pong) =================
    {   // prologue: tile 0 -> K0
        *(uint4*)(K0 + sr * 72 + sc0)     = *(const uint4*)(kbase + (long long)sr * D_MODEL + sc0);
        *(uint4*)(K0 + sr * 72 + sc0 + 8) = *(const uint4*)(kbase + (long long)sr * D_MODEL + sc0 + 8);
#pragma unroll
        for (int nt = 0; nt < 4; nt++)
#pragma unroll
            for (int reg = 0; reg < 4; reg++)
                ebc[nt][reg] = ebp[(long long)reg * L_SEQ + nt * 16];
    }
    __syncthreads();

    for (int t = 0; t < 32; t++) {
        unsigned short* cur = (t & 1) ? K1 : K0;
        unsigned short* nxt = (t & 1) ? K0 : K1;
        uint4 ka, kb;
        float ebn[4][4];
        if (t < 31) {
            const int m1 = (t + 1) * 64;
            ka = *(const uint4*)(kbase + (long long)(m1 + sr) * D_MODEL + sc0);
            kb = *(const uint4*)(kbase + (long long)(m1 + sr) * D_MODEL + sc0 + 8);
#pragma unroll
            for (int nt = 0; nt < 4; nt++)
#pragma unroll
                for (int reg = 0; reg < 4; reg++)
                    ebn[nt][reg] = ebp[(long long)reg * L_SEQ + m1 + nt * 16];
        }

        f32x4 acc[4];
#pragma unroll
        for (int nt = 0; nt < 4; nt++) acc[nt] = (f32x4){0.f, 0.f, 0.f, 0.f};
#pragma unroll
        for (int nt = 0; nt < 4; nt++)
#pragma unroll
            for (int kc = 0; kc < 2; kc++) {
                short8 bk = *(const short8*)(cur + (nt * 16 + col) * 72 + quad * 8 + kc * 32);
                acc[nt] = __builtin_amdgcn_mfma_f32_16x16x32_bf16(aq[kc], bk, acc[nt], 0, 0, 0);
            }

        float sv[4][4];
#pragma unroll
        for (int nt = 0; nt < 4; nt++)
#pragma unroll
            for (int reg = 0; reg < 4; reg++)
                sv[nt][reg] = acc[nt][reg] * 0.125f + ENERGY_SCALE * ebc[nt][reg];

#pragma unroll
        for (int reg = 0; reg < 4; reg++) {
            float tm = fmaxf(fmaxf(sv[0][reg], sv[1][reg]), fmaxf(sv[2][reg], sv[3][reg]));
#pragma unroll
            for (int off = 8; off > 0; off >>= 1) tm = fmaxf(tm, __shfl_xor(tm, off, 64));
            float nm = fmaxf(rowM[reg], tm);
            float tsum = __expf(sv[0][reg] - nm) + __expf(sv[1][reg] - nm) +
                         __expf(sv[2][reg] - nm) + __expf(sv[3][reg] - nm);
#pragma unroll
            for (int off = 8; off > 0; off >>= 1) tsum += __shfl_xor(tsum, off, 64);
            rowS[reg] = rowS[reg] * __expf(rowM[reg] - nm) + tsum;
            rowM[reg] = nm;
        }

        if (t < 31) {
            *(uint4*)(nxt + sr * 72 + sc0)     = ka;
            *(uint4*)(nxt + sr * 72 + sc0 + 8) = kb;
        }
        __syncthreads();
        if (t < 31) {
#pragma unroll
            for (int nt = 0; nt < 4; nt++)
#pragma unroll
                for (int reg = 0; reg < 4; reg++)
                    ebc[nt][reg] = ebn[nt][reg];
        }
    }

    float invS[4];
#pragma unroll
    for (int reg = 0; reg < 4; reg++) invS[reg] = 1.f / rowS[reg];

    // ================= sweep 2: write attn, ctx = P V (K/V ping-pong) =================
    f32x4 ctx[4];
#pragma unroll
    for (int nt = 0; nt < 4; nt++) ctx[nt] = (f32x4){0.f, 0.f, 0.f, 0.f};

    unsigned short* Psw = Ps + w * 16 * 72;
    float* aob = attn_out + (((long long)(b * NUM_HEADS + h)) * L_SEQ + l0 + w * 16 + quad * 4) * L_SEQ + col;

    {   // prologue: tile 0 -> K0, V0
        *(uint4*)(K0 + sr * 72 + sc0)     = *(const uint4*)(kbase + (long long)sr * D_MODEL + sc0);
        *(uint4*)(K0 + sr * 72 + sc0 + 8) = *(const uint4*)(kbase + (long long)sr * D_MODEL + sc0 + 8);
        *(uint4*)(V0 + sr * 72 + sc0)     = *(const uint4*)(vbase + (long long)sr * L_SEQ + sc0);
        *(uint4*)(V0 + sr * 72 + sc0 + 8) = *(const uint4*)(vbase + (long long)sr * L_SEQ + sc0 + 8);
#pragma unroll
        for (int nt = 0; nt < 4; nt++)
#pragma unroll
            for (int reg = 0; reg < 4; reg++)
                ebc[nt][reg] = ebp[(long long)reg * L_SEQ + nt * 16];
    }
    __syncthreads();

    for (int t = 0; t < 32; t++) {
        const int m0 = t * 64;
        unsigned short* curK = (t & 1) ? K1 : K0;
        unsigned short* nxtK = (t & 1) ? K0 : K1;
        unsigned short* curV = (t & 1) ? V1 : V0;
        unsigned short* nxtV = (t & 1) ? V0 : V1;
        uint4 ka, kb, va, vb;
        float ebn[4][4];
        if (t < 31) {
            const int m1 = m0 + 64;
            ka = *(const uint4*)(kbase + (long long)(m1 + sr) * D_MODEL + sc0);
            kb = *(const uint4*)(kbase + (long long)(m1 + sr) * D_MODEL + sc0 + 8);
            va = *(const uint4*)(vbase + (long long)sr * L_SEQ + m1 + sc0);
            vb = *(const uint4*)(vbase + (long long)sr * L_SEQ + m1 + sc0 + 8);
#pragma unroll
            for (int nt = 0; nt < 4; nt++)
#pragma unroll
                for (int reg = 0; reg < 4; reg++)
                    ebn[nt][reg] = ebp[(long long)reg * L_SEQ + m1 + nt * 16];
        }

        f32x4 acc[4];
#pragma unroll
        for (int nt = 0; nt < 4; nt++) acc[nt] = (f32x4){0.f, 0.f, 0.f, 0.f};
#pragma unroll
        for (int nt = 0; nt < 4; nt++)
#pragma unroll
            for (int kc = 0; kc < 2; kc++) {
                short8 bk = *(const short8*)(curK + (nt * 16 + col) * 72 + quad * 8 + kc * 32);
                acc[nt] = __builtin_amdgcn_mfma_f32_16x16x32_bf16(aq[kc], bk, acc[nt], 0, 0, 0);
            }

        float pv[4][4];
#pragma unroll
        for (int nt = 0; nt < 4; nt++)
#pragma unroll
            for (int reg = 0; reg < 4; reg++) {
                float s = acc[nt][reg] * 0.125f + ENERGY_SCALE * ebc[nt][reg];
                float p = __expf(s - rowM[reg]) * invS[reg];
                pv[nt][reg] = p;
                Psw[(quad * 4 + reg) * 72 + nt * 16 + col] = f2bf(p);
            }

        short8 ap[2];
#pragma unroll
        for (int kc = 0; kc < 2; kc++)
            ap[kc] = *(const short8*)(Psw + col * 72 + quad * 8 + kc * 32);
#pragma unroll
        for (int nt = 0; nt < 4; nt++)
#pragma unroll
            for (int kc = 0; kc < 2; kc++) {
                short8 bv = *(const short8*)(curV + (nt * 16 + col) * 72 + quad * 8 + kc * 32);
                ctx[nt] = __builtin_amdgcn_mfma_f32_16x16x32_bf16(ap[kc], bv, ctx[nt], 0, 0, 0);
            }

        // attn stores after MFMAs so they drain behind matrix work
#pragma unroll
        for (int nt = 0; nt < 4; nt++)
#pragma unroll
            for (int reg = 0; reg < 4; reg++)
                aob[(long long)reg * L_SEQ + m0 + nt * 16] = pv[nt][reg];

        if (t < 31) {
            *(uint4*)(nxtK + sr * 72 + sc0)     = ka;
            *(uint4*)(nxtK + sr * 72 + sc0 + 8) = kb;
            *(uint4*)(nxtV + sr * 72 + sc0)     = va;
            *(uint4*)(nxtV + sr * 72 + sc0 + 8) = vb;
        }
        __syncthreads();
        if (t < 31) {
#pragma unroll
            for (int nt = 0; nt < 4; nt++)
#pragma unroll
                for (int reg = 0; reg < 4; reg++)
                    ebc[nt][reg] = ebn[nt][reg];
        }
    }

#pragma unroll
    for (int nt = 0; nt < 4; nt++)
#pragma unroll
        for (int reg = 0; reg < 4; reg++)
            CTXh[((long long)b * L_SEQ + l0 + w * 16 + quad * 4 + reg) * D_MODEL + h * DK + nt * 16 + col] =
                f2bf(ctx[nt][reg]);
}

extern "C" void kernel_launch(void* const* d_in, const int* in_sizes, int n_in,
                              void* d_out, int out_size, void* d_ws, size_t ws_size,
                              hipStream_t stream) {
    const float* x    = (const float*)d_in[0];
    const float* wq   = (const float*)d_in[1];
    const float* wk   = (const float*)d_in[2];
    const float* wv   = (const float*)d_in[3];
    const float* wo_w = (const float*)d_in[4];
    const float* wo_b = (const float*)d_in[5];
    const float* ep_w = (const float*)d_in[6];
    const float* ep_b = (const float*)d_in[7];
    const float* en_g = (const float*)d_in[8];
    const float* en_b = (const float*)d_in[9];
    const float* ln_g = (const float*)d_in[10];
    const float* ln_b = (const float*)d_in[11];

    float* out_final = (float*)d_out;
    float* attn_out  = out_final + (long long)BATCH * L_SEQ * D_MODEL;

    const long long MD = (long long)BATCH * L_SEQ * D_MODEL;   // 4,194,304
    const long long WN = (long long)D_MODEL * D_MODEL;         // 1,048,576

    float* EB = (float*)d_ws;                                  // [B,L,L] fp32
    float* EP = EB + (long long)BATCH * L_SEQ * L_SEQ;         // MD fp32 (also OUT)
    unsigned short* Xh   = (unsigned short*)(EP + MD);
    unsigned short* Qh   = Xh + MD;
    unsigned short* Kh   = Qh + MD;
    unsigned short* Vf   = Kh + MD;
    unsigned short* Vt   = Vf + MD;
    unsigned short* EFh  = Vt + MD;
    unsigned short* CTXh = EFh + MD;
    unsigned short* wqh  = CTXh + MD;
    unsigned short* wkh  = wqh + WN;
    unsigned short* wvh  = wkh + WN;
    unsigned short* eph  = wvh + WN;
    unsigned short* woh  = eph + WN;
    float* OUT = EP;                                           // EP dead after ln

    const int M = BATCH * L_SEQ;                               // 4096
    dim3 blk(256);

    cvt6<<<dim3((unsigned)(MD / 1024), 6), blk, 0, stream>>>(
        x, wq, wk, wv, ep_w, wo_w, Xh, wqh, wkh, wvh, eph, woh,
        MD, WN, WN, WN, WN, WN);

    proj_gemm<<<dim3(D_MODEL / 128, M / 128, 4), blk, 0, stream>>>(
        Xh, wqh, wkh, wvh, eph, ep_b, Qh, Kh, Vf, EP);

    ln_rows<<<dim3(M), blk, 0, stream>>>(EP, nullptr, en_g, en_b, nullptr, EFh);

    gemm_bf16<<<dim3(L_SEQ / 128, L_SEQ / 128, BATCH), blk, 0, stream>>>(
        EFh, EFh, nullptr, EB, nullptr, L_SEQ, D_MODEL,
        (long long)L_SEQ * D_MODEL, (long long)L_SEQ * D_MODEL,
        (long long)L_SEQ * L_SEQ);

    transpose_v<<<dim3(L_SEQ / 64, NUM_HEADS, BATCH), blk, 0, stream>>>(Vf, Vt);

    attn_mfma<<<dim3(L_SEQ / 64, NUM_HEADS, BATCH), blk, 0, stream>>>(
        Qh, Kh, Vt, EB, attn_out, CTXh);

    gemm_bf16<<<dim3(D_MODEL / 128, M / 128, 1), blk, 0, stream>>>(
        CTXh, woh, wo_b, OUT, nullptr, D_MODEL, D_MODEL, 0, 0, 0);

    ln_rows<<<dim3(M), blk, 0, stream>>>(OUT, x, ln_g, ln_b, out_final, nullptr);
}

// Round 6
// 894.869 us; speedup vs baseline: 1.2177x; 1.0117x over previous
//
#include <hip/hip_runtime.h>
#include <math.h>

#define D_MODEL 1024
#define NUM_HEADS 16
#define DK 64
#define L_SEQ 2048
#define BATCH 2
#define LN_EPS 1e-5f
#define ENERGY_SCALE 0.1f

typedef __attribute__((ext_vector_type(8))) short short8;
typedef __attribute__((ext_vector_type(4))) float f32x4;

__device__ __forceinline__ float waveReduceSum(float v) {
#pragma unroll
    for (int off = 32; off > 0; off >>= 1) v += __shfl_xor(v, off, 64);
    return v;
}
__device__ __forceinline__ float waveReduceMax(float v) {
#pragma unroll
    for (int off = 32; off > 0; off >>= 1) v = fmaxf(v, __shfl_xor(v, off, 64));
    return v;
}

__device__ __forceinline__ unsigned short f2bf(float f) {
    unsigned int u = __float_as_uint(f);
    u += 0x7fff + ((u >> 16) & 1);          // round-to-nearest-even
    return (unsigned short)(u >> 16);
}
__device__ __forceinline__ float bf2f(unsigned short u) {
    return __uint_as_float((unsigned int)u << 16);
}

// ---------------- fp32 -> bf16 convert, 6 matrices in one launch ----------------
__global__ __launch_bounds__(256) void cvt6(
    const float* s0, const float* s1, const float* s2,
    const float* s3, const float* s4, const float* s5,
    unsigned short* d0, unsigned short* d1, unsigned short* d2,
    unsigned short* d3, unsigned short* d4, unsigned short* d5,
    long long n0, long long n1, long long n2, long long n3, long long n4, long long n5)
{
    const float* s; unsigned short* d; long long n;
    switch (blockIdx.y) {
        case 0: s = s0; d = d0; n = n0; break;
        case 1: s = s1; d = d1; n = n1; break;
        case 2: s = s2; d = d2; n = n2; break;
        case 3: s = s3; d = d3; n = n3; break;
        case 4: s = s4; d = d4; n = n4; break;
        default: s = s5; d = d5; n = n5; break;
    }
    long long i = ((long long)blockIdx.x * 256 + threadIdx.x) * 4;
    if (i >= n) return;
    float4 v = *(const float4*)(s + i);
    ushort4 o;
    o.x = f2bf(v.x); o.y = f2bf(v.y); o.z = f2bf(v.z); o.w = f2bf(v.w);
    *(ushort4*)(d + i) = o;
}

// ---------------- bf16 MFMA GEMM (verified round-3 version) ----------------
__global__ __launch_bounds__(256) void gemm_bf16(
    const unsigned short* __restrict__ A, const unsigned short* __restrict__ B,
    const float* __restrict__ bias, float* __restrict__ Cf, unsigned short* __restrict__ Ch,
    int N, int K, long long sA, long long sB, long long sC)
{
    A += (long long)blockIdx.z * sA;
    B += (long long)blockIdx.z * sB;
    __shared__ unsigned short As[128 * 72];
    __shared__ unsigned short Bs[128 * 72];
    const int tid = threadIdx.x;
    const int lane = tid & 63, w = tid >> 6;
    const int quad = lane >> 4, col = lane & 15;
    const int wm = w & 1, wn = w >> 1;
    const int row0 = blockIdx.y * 128, col0 = blockIdx.x * 128;

    f32x4 acc[4][4];
#pragma unroll
    for (int mt = 0; mt < 4; mt++)
#pragma unroll
        for (int nt = 0; nt < 4; nt++) acc[mt][nt] = (f32x4){0.f, 0.f, 0.f, 0.f};

    for (int k0 = 0; k0 < K; k0 += 64) {
        __syncthreads();
#pragma unroll
        for (int p = 0; p < 4; p++) {
            int u = tid + p * 256;
            int r = u >> 3;
            int c = (u & 7) * 8;
            *(uint4*)(As + r * 72 + c) = *(const uint4*)(A + (long long)(row0 + r) * K + k0 + c);
            *(uint4*)(Bs + r * 72 + c) = *(const uint4*)(B + (long long)(col0 + r) * K + k0 + c);
        }
        __syncthreads();
#pragma unroll
        for (int kc = 0; kc < 2; kc++) {
            short8 af[4], bfr[4];
#pragma unroll
            for (int mt = 0; mt < 4; mt++)
                af[mt] = *(const short8*)(As + (wm * 64 + mt * 16 + col) * 72 + quad * 8 + kc * 32);
#pragma unroll
            for (int nt = 0; nt < 4; nt++)
                bfr[nt] = *(const short8*)(Bs + (wn * 64 + nt * 16 + col) * 72 + quad * 8 + kc * 32);
#pragma unroll
            for (int mt = 0; mt < 4; mt++)
#pragma unroll
                for (int nt = 0; nt < 4; nt++)
                    acc[mt][nt] = __builtin_amdgcn_mfma_f32_16x16x32_bf16(af[mt], bfr[nt], acc[mt][nt], 0, 0, 0);
        }
    }

#pragma unroll
    for (int mt = 0; mt < 4; mt++)
#pragma unroll
        for (int nt = 0; nt < 4; nt++)
#pragma unroll
            for (int reg = 0; reg < 4; reg++) {
                long long row = row0 + wm * 64 + mt * 16 + quad * 4 + reg;
                int c = col0 + wn * 64 + nt * 16 + col;
                float v = acc[mt][nt][reg];
                if (bias) v += bias[c];
                if (Cf) Cf[blockIdx.z * sC + row * N + c] = v;
                else    Ch[blockIdx.z * sC + row * N + c] = f2bf(v);
            }
}

// ---------------- fused projections (verified round-3 version) ----------------
__global__ __launch_bounds__(256) void proj_gemm(
    const unsigned short* __restrict__ Xh,
    const unsigned short* __restrict__ wqh, const unsigned short* __restrict__ wkh,
    const unsigned short* __restrict__ wvh, const unsigned short* __restrict__ eph,
    const float* __restrict__ ep_b,
    unsigned short* __restrict__ Qh, unsigned short* __restrict__ Kh,
    unsigned short* __restrict__ Vf, float* __restrict__ EP)
{
    const unsigned short* B;
    switch (blockIdx.z) {
        case 0: B = wqh; break;
        case 1: B = wkh; break;
        case 2: B = wvh; break;
        default: B = eph; break;
    }
    __shared__ unsigned short As[128 * 72];
    __shared__ unsigned short Bs[128 * 72];
    const int tid = threadIdx.x;
    const int lane = tid & 63, w = tid >> 6;
    const int quad = lane >> 4, col = lane & 15;
    const int wm = w & 1, wn = w >> 1;
    const int row0 = blockIdx.y * 128, col0 = blockIdx.x * 128;
    const int K = D_MODEL, N = D_MODEL;

    f32x4 acc[4][4];
#pragma unroll
    for (int mt = 0; mt < 4; mt++)
#pragma unroll
        for (int nt = 0; nt < 4; nt++) acc[mt][nt] = (f32x4){0.f, 0.f, 0.f, 0.f};

    for (int k0 = 0; k0 < K; k0 += 64) {
        __syncthreads();
#pragma unroll
        for (int p = 0; p < 4; p++) {
            int u = tid + p * 256;
            int r = u >> 3;
            int c = (u & 7) * 8;
            *(uint4*)(As + r * 72 + c) = *(const uint4*)(Xh + (long long)(row0 + r) * K + k0 + c);
            *(uint4*)(Bs + r * 72 + c) = *(const uint4*)(B + (long long)(col0 + r) * K + k0 + c);
        }
        __syncthreads();
#pragma unroll
        for (int kc = 0; kc < 2; kc++) {
            short8 af[4], bfr[4];
#pragma unroll
            for (int mt = 0; mt < 4; mt++)
                af[mt] = *(const short8*)(As + (wm * 64 + mt * 16 + col) * 72 + quad * 8 + kc * 32);
#pragma unroll
            for (int nt = 0; nt < 4; nt++)
                bfr[nt] = *(const short8*)(Bs + (wn * 64 + nt * 16 + col) * 72 + quad * 8 + kc * 32);
#pragma unroll
            for (int mt = 0; mt < 4; mt++)
#pragma unroll
                for (int nt = 0; nt < 4; nt++)
                    acc[mt][nt] = __builtin_amdgcn_mfma_f32_16x16x32_bf16(af[mt], bfr[nt], acc[mt][nt], 0, 0, 0);
        }
    }

    unsigned short* Hout = (blockIdx.z == 0) ? Qh : (blockIdx.z == 1) ? Kh : Vf;
#pragma unroll
    for (int mt = 0; mt < 4; mt++)
#pragma unroll
        for (int nt = 0; nt < 4; nt++)
#pragma unroll
            for (int reg = 0; reg < 4; reg++) {
                long long row = row0 + wm * 64 + mt * 16 + quad * 4 + reg;
                int c = col0 + wn * 64 + nt * 16 + col;
                float v = acc[mt][nt][reg];
                if (blockIdx.z == 3) EP[row * N + c] = v + ep_b[c];
                else                 Hout[row * N + c] = f2bf(v);
            }
}

// ---------------- LayerNorm rows ----------------
__global__ __launch_bounds__(256) void ln_rows(
    const float* __restrict__ in, const float* __restrict__ res,
    const float* __restrict__ g, const float* __restrict__ bta,
    float* __restrict__ outf, unsigned short* __restrict__ outh)
{
    const long long row = blockIdx.x;
    const float* ip = in + row * D_MODEL;
    const float* rp = res ? res + row * D_MODEL : nullptr;
    const int tid = threadIdx.x;
    float vals[4];
    float s = 0.f, ss = 0.f;
#pragma unroll
    for (int j = 0; j < 4; j++) {
        int idx = tid + j * 256;
        float v = ip[idx];
        if (rp) v += rp[idx];
        vals[j] = v; s += v; ss += v * v;
    }
    __shared__ float sred[4], ssred[4];
    s = waveReduceSum(s); ss = waveReduceSum(ss);
    int wave = tid >> 6, lane = tid & 63;
    if (lane == 0) { sred[wave] = s; ssred[wave] = ss; }
    __syncthreads();
    float ts = sred[0] + sred[1] + sred[2] + sred[3];
    float tss = ssred[0] + ssred[1] + ssred[2] + ssred[3];
    float mu = ts * (1.f / D_MODEL);
    float var = tss * (1.f / D_MODEL) - mu * mu;
    float rs = rsqrtf(var + LN_EPS);
#pragma unroll
    for (int j = 0; j < 4; j++) {
        int idx = tid + j * 256;
        float o = (vals[j] - mu) * rs * g[idx] + bta[idx];
        if (outf) outf[row * D_MODEL + idx] = o;
        else      outh[row * D_MODEL + idx] = f2bf(o);
    }
}

// ---------------- V transpose ----------------
__global__ __launch_bounds__(256) void transpose_v(
    const unsigned short* __restrict__ V, unsigned short* __restrict__ Vt)
{
    const int m0 = blockIdx.x * 64, h = blockIdx.y, b = blockIdx.z;
    __shared__ unsigned int t[64][65];
    const int tid = threadIdx.x;
    {
        int r = tid >> 4, c4 = (tid & 15) * 4;
#pragma unroll
        for (int i = 0; i < 4; i++) {
            int row = r + i * 16;
            ushort4 v = *(const ushort4*)(V + ((long long)b * L_SEQ + m0 + row) * D_MODEL + h * DK + c4);
            t[row][c4] = v.x; t[row][c4 + 1] = v.y; t[row][c4 + 2] = v.z; t[row][c4 + 3] = v.w;
        }
    }
    __syncthreads();
    const int lane = tid & 63, wv = tid >> 6;
#pragma unroll
    for (int i = 0; i < 16; i++) {
        int d = wv * 16 + i;
        Vt[(((long long)(b * NUM_HEADS + h)) * DK + d) * L_SEQ + m0 + lane] = (unsigned short)t[lane][d];
    }
}

// ---------------- stats kernels for the analytic softmax shift ----------------
// ebmax[b*L + l] = max_m EB[b,l,m]
__global__ __launch_bounds__(256) void eb_rowmax(
    const float* __restrict__ EB, float* __restrict__ ebmax)
{
    const long long row = blockIdx.x;
    const float* p = EB + row * L_SEQ;
    const int tid = threadIdx.x;
    float4 a = *(const float4*)(p + tid * 4);
    float4 c = *(const float4*)(p + 1024 + tid * 4);
    float m = fmaxf(fmaxf(fmaxf(a.x, a.y), fmaxf(a.z, a.w)),
                    fmaxf(fmaxf(c.x, c.y), fmaxf(c.z, c.w)));
    m = waveReduceMax(m);
    __shared__ float red[4];
    int wave = tid >> 6, lane = tid & 63;
    if (lane == 0) red[wave] = m;
    __syncthreads();
    if (tid == 0)
        ebmax[row] = fmaxf(fmaxf(red[0], red[1]), fmaxf(red[2], red[3]));
}

// qn[(b*H+h)*L + l] = |q_{b,l,h}| ; kn likewise
__global__ __launch_bounds__(256) void qk_stats(
    const unsigned short* __restrict__ Qh, const unsigned short* __restrict__ Kh,
    float* __restrict__ qn, float* __restrict__ kn)
{
    const int l0 = blockIdx.x * 64, h = blockIdx.y, b = blockIdx.z;
    const int tid = threadIdx.x;
    const int r = tid >> 2, p4 = (tid & 3) * 16;
    const unsigned short* q = Qh + ((long long)b * L_SEQ + l0 + r) * D_MODEL + h * DK + p4;
    const unsigned short* k = Kh + ((long long)b * L_SEQ + l0 + r) * D_MODEL + h * DK + p4;
    float sq = 0.f, sk = 0.f;
#pragma unroll
    for (int i = 0; i < 16; i++) {
        float qv = bf2f(q[i]); sq += qv * qv;
        float kv = bf2f(k[i]); sk += kv * kv;
    }
    sq += __shfl_xor(sq, 1, 64); sq += __shfl_xor(sq, 2, 64);
    sk += __shfl_xor(sk, 1, 64); sk += __shfl_xor(sk, 2, 64);
    if ((tid & 3) == 0) {
        long long idx = ((long long)(b * NUM_HEADS + h)) * L_SEQ + l0 + r;
        qn[idx] = sqrtf(sq);
        kn[idx] = sqrtf(sk);
    }
}

// kmax[bh] = max_l kn[bh*L + l]
__global__ __launch_bounds__(256) void kmax_red(
    const float* __restrict__ kn, float* __restrict__ kmax)
{
    const long long bh = blockIdx.x;
    const float* p = kn + bh * L_SEQ;
    const int tid = threadIdx.x;
    float4 a = *(const float4*)(p + tid * 4);
    float4 c = *(const float4*)(p + 1024 + tid * 4);
    float m = fmaxf(fmaxf(fmaxf(a.x, a.y), fmaxf(a.z, a.w)),
                    fmaxf(fmaxf(c.x, c.y), fmaxf(c.z, c.w)));
    m = waveReduceMax(m);
    __shared__ float red[4];
    int wave = tid >> 6, lane = tid & 63;
    if (lane == 0) red[wave] = m;
    __syncthreads();
    if (tid == 0)
        kmax[bh] = fmaxf(fmaxf(red[0], red[1]), fmaxf(red[2], red[3]));
}

// ---------------- MFMA attention: analytic shift, ping-pong staging ----------------
// Sweep 1: rowS = sum exp(s - Mhat), no cross-lane ops per tile.
// Sweep 2: p = exp(s - Mhat)/rowS -> attn_out, P@V via MFMA.
__global__ __launch_bounds__(256) void attn_mfma(
    const unsigned short* __restrict__ Qh, const unsigned short* __restrict__ Kh,
    const unsigned short* __restrict__ Vt, const float* __restrict__ EB,
    const float* __restrict__ ebmax, const float* __restrict__ qn,
    const float* __restrict__ kmax,
    float* __restrict__ attn_out, unsigned short* __restrict__ CTXh)
{
    __shared__ unsigned short smem[5 * 64 * 72];
    unsigned short* K0 = smem;
    unsigned short* K1 = smem + 4608;
    unsigned short* V0 = smem + 2 * 4608;
    unsigned short* V1 = smem + 3 * 4608;
    unsigned short* Ps = smem + 4 * 4608;

    const int tid = threadIdx.x;
    const int lane = tid & 63, w = tid >> 6;
    const int quad = lane >> 4, col = lane & 15;
    const int l0 = blockIdx.x * 64;
    const int h = blockIdx.y, b = blockIdx.z;

    // Q fragments direct from global (A-layout: row=col, k=kc*32+quad*8+j)
    short8 aq[2];
    {
        const unsigned short* qrow = Qh + ((long long)b * L_SEQ + l0 + w * 16 + col) * D_MODEL + h * DK;
        aq[0] = *(const short8*)(qrow + quad * 8);
        aq[1] = *(const short8*)(qrow + 32 + quad * 8);
    }

    // analytic upper bound on row max: Mhat >= max_m (qk/8 + 0.1*eb)
    float Mhat[4];
    {
        const float km = kmax[b * NUM_HEADS + h];
#pragma unroll
        for (int reg = 0; reg < 4; reg++) {
            int row = l0 + w * 16 + quad * 4 + reg;
            float qb = qn[((long long)(b * NUM_HEADS + h)) * L_SEQ + row];
            Mhat[reg] = ENERGY_SCALE * ebmax[(long long)b * L_SEQ + row] +
                        qb * km * 0.125f + 0.02f;
        }
    }

    const float* ebp = EB + ((long long)b * L_SEQ + l0 + w * 16 + quad * 4) * L_SEQ + col;
    const unsigned short* kbase = Kh + ((long long)b * L_SEQ) * D_MODEL + h * DK;
    const unsigned short* vbase = Vt + ((long long)(b * NUM_HEADS + h)) * DK * L_SEQ;

    const int sr = tid >> 2, sc0 = (tid & 3) * 16;

    float rowSacc[4] = {0.f, 0.f, 0.f, 0.f};
    float ebc[4][4];

    // ================= sweep 1: rowS only (K ping-pong, no cross-lane) =================
    {
        *(uint4*)(K0 + sr * 72 + sc0)     = *(const uint4*)(kbase + (long long)sr * D_MODEL + sc0);
        *(uint4*)(K0 + sr * 72 + sc0 + 8) = *(const uint4*)(kbase + (long long)sr * D_MODEL + sc0 + 8);
#pragma unroll
        for (int nt = 0; nt < 4; nt++)
#pragma unroll
            for (int reg = 0; reg < 4; reg++)
                ebc[nt][reg] = ebp[(long long)reg * L_SEQ + nt * 16];
    }
    __syncthreads();

    for (int t = 0; t < 32; t++) {
        unsigned short* cur = (t & 1) ? K1 : K0;
        unsigned short* nxt = (t & 1) ? K0 : K1;
        uint4 ka, kb;
        float ebn[4][4];
        if (t < 31) {
            const int m1 = (t + 1) * 64;
            ka = *(const uint4*)(kbase + (long long)(m1 + sr) * D_MODEL + sc0);
            kb = *(const uint4*)(kbase + (long long)(m1 + sr) * D_MODEL + sc0 + 8);
#pragma unroll
            for (int nt = 0; nt < 4; nt++)
#pragma unroll
                for (int reg = 0; reg < 4; reg++)
                    ebn[nt][reg] = ebp[(long long)reg * L_SEQ + m1 + nt * 16];
        }

        f32x4 acc[4];
#pragma unroll
        for (int nt = 0; nt < 4; nt++) acc[nt] = (f32x4){0.f, 0.f, 0.f, 0.f};
#pragma unroll
        for (int nt = 0; nt < 4; nt++)
#pragma unroll
            for (int kc = 0; kc < 2; kc++) {
                short8 bk = *(const short8*)(cur + (nt * 16 + col) * 72 + quad * 8 + kc * 32);
                acc[nt] = __builtin_amdgcn_mfma_f32_16x16x32_bf16(aq[kc], bk, acc[nt], 0, 0, 0);
            }

#pragma unroll
        for (int nt = 0; nt < 4; nt++)
#pragma unroll
            for (int reg = 0; reg < 4; reg++) {
                float s = acc[nt][reg] * 0.125f + ENERGY_SCALE * ebc[nt][reg];
                rowSacc[reg] += __expf(s - Mhat[reg]);
            }

        if (t < 31) {
            *(uint4*)(nxt + sr * 72 + sc0)     = ka;
            *(uint4*)(nxt + sr * 72 + sc0 + 8) = kb;
        }
        __syncthreads();
        if (t < 31) {
#pragma unroll
            for (int nt = 0; nt < 4; nt++)
#pragma unroll
                for (int reg = 0; reg < 4; reg++)
                    ebc[nt][reg] = ebn[nt][reg];
        }
    }

    float invS[4];
#pragma unroll
    for (int reg = 0; reg < 4; reg++) {
        float v = rowSacc[reg];
#pragma unroll
        for (int off = 8; off > 0; off >>= 1) v += __shfl_xor(v, off, 64);
        invS[reg] = 1.f / v;
    }

    // ================= sweep 2: write attn, ctx = P V (K/V ping-pong) =================
    f32x4 ctx[4];
#pragma unroll
    for (int nt = 0; nt < 4; nt++) ctx[nt] = (f32x4){0.f, 0.f, 0.f, 0.f};

    unsigned short* Psw = Ps + w * 16 * 72;
    float* aob = attn_out + (((long long)(b * NUM_HEADS + h)) * L_SEQ + l0 + w * 16 + quad * 4) * L_SEQ + col;

    {
        *(uint4*)(K0 + sr * 72 + sc0)     = *(const uint4*)(kbase + (long long)sr * D_MODEL + sc0);
        *(uint4*)(K0 + sr * 72 + sc0 + 8) = *(const uint4*)(kbase + (long long)sr * D_MODEL + sc0 + 8);
        *(uint4*)(V0 + sr * 72 + sc0)     = *(const uint4*)(vbase + (long long)sr * L_SEQ + sc0);
        *(uint4*)(V0 + sr * 72 + sc0 + 8) = *(const uint4*)(vbase + (long long)sr * L_SEQ + sc0 + 8);
#pragma unroll
        for (int nt = 0; nt < 4; nt++)
#pragma unroll
            for (int reg = 0; reg < 4; reg++)
                ebc[nt][reg] = ebp[(long long)reg * L_SEQ + nt * 16];
    }
    __syncthreads();

    for (int t = 0; t < 32; t++) {
        const int m0 = t * 64;
        unsigned short* curK = (t & 1) ? K1 : K0;
        unsigned short* nxtK = (t & 1) ? K0 : K1;
        unsigned short* curV = (t & 1) ? V1 : V0;
        unsigned short* nxtV = (t & 1) ? V0 : V1;
        uint4 ka, kb, va, vb;
        float ebn[4][4];
        if (t < 31) {
            const int m1 = m0 + 64;
            ka = *(const uint4*)(kbase + (long long)(m1 + sr) * D_MODEL + sc0);
            kb = *(const uint4*)(kbase + (long long)(m1 + sr) * D_MODEL + sc0 + 8);
            va = *(const uint4*)(vbase + (long long)sr * L_SEQ + m1 + sc0);
            vb = *(const uint4*)(vbase + (long long)sr * L_SEQ + m1 + sc0 + 8);
#pragma unroll
            for (int nt = 0; nt < 4; nt++)
#pragma unroll
                for (int reg = 0; reg < 4; reg++)
                    ebn[nt][reg] = ebp[(long long)reg * L_SEQ + m1 + nt * 16];
        }

        f32x4 acc[4];
#pragma unroll
        for (int nt = 0; nt < 4; nt++) acc[nt] = (f32x4){0.f, 0.f, 0.f, 0.f};
#pragma unroll
        for (int nt = 0; nt < 4; nt++)
#pragma unroll
            for (int kc = 0; kc < 2; kc++) {
                short8 bk = *(const short8*)(curK + (nt * 16 + col) * 72 + quad * 8 + kc * 32);
                acc[nt] = __builtin_amdgcn_mfma_f32_16x16x32_bf16(aq[kc], bk, acc[nt], 0, 0, 0);
            }

        float pv[4][4];
#pragma unroll
        for (int nt = 0; nt < 4; nt++)
#pragma unroll
            for (int reg = 0; reg < 4; reg++) {
                float s = acc[nt][reg] * 0.125f + ENERGY_SCALE * ebc[nt][reg];
                float p = __expf(s - Mhat[reg]) * invS[reg];
                pv[nt][reg] = p;
                Psw[(quad * 4 + reg) * 72 + nt * 16 + col] = f2bf(p);
            }

        short8 ap[2];
#pragma unroll
        for (int kc = 0; kc < 2; kc++)
            ap[kc] = *(const short8*)(Psw + col * 72 + quad * 8 + kc * 32);
#pragma unroll
        for (int nt = 0; nt < 4; nt++)
#pragma unroll
            for (int kc = 0; kc < 2; kc++) {
                short8 bv = *(const short8*)(curV + (nt * 16 + col) * 72 + quad * 8 + kc * 32);
                ctx[nt] = __builtin_amdgcn_mfma_f32_16x16x32_bf16(ap[kc], bv, ctx[nt], 0, 0, 0);
            }

#pragma unroll
        for (int nt = 0; nt < 4; nt++)
#pragma unroll
            for (int reg = 0; reg < 4; reg++)
                aob[(long long)reg * L_SEQ + m0 + nt * 16] = pv[nt][reg];

        if (t < 31) {
            *(uint4*)(nxtK + sr * 72 + sc0)     = ka;
            *(uint4*)(nxtK + sr * 72 + sc0 + 8) = kb;
            *(uint4*)(nxtV + sr * 72 + sc0)     = va;
            *(uint4*)(nxtV + sr * 72 + sc0 + 8) = vb;
        }
        __syncthreads();
        if (t < 31) {
#pragma unroll
            for (int nt = 0; nt < 4; nt++)
#pragma unroll
                for (int reg = 0; reg < 4; reg++)
                    ebc[nt][reg] = ebn[nt][reg];
        }
    }

#pragma unroll
    for (int nt = 0; nt < 4; nt++)
#pragma unroll
        for (int reg = 0; reg < 4; reg++)
            CTXh[((long long)b * L_SEQ + l0 + w * 16 + quad * 4 + reg) * D_MODEL + h * DK + nt * 16 + col] =
                f2bf(ctx[nt][reg]);
}

extern "C" void kernel_launch(void* const* d_in, const int* in_sizes, int n_in,
                              void* d_out, int out_size, void* d_ws, size_t ws_size,
                              hipStream_t stream) {
    const float* x    = (const float*)d_in[0];
    const float* wq   = (const float*)d_in[1];
    const float* wk   = (const float*)d_in[2];
    const float* wv   = (const float*)d_in[3];
    const float* wo_w = (const float*)d_in[4];
    const float* wo_b = (const float*)d_in[5];
    const float* ep_w = (const float*)d_in[6];
    const float* ep_b = (const float*)d_in[7];
    const float* en_g = (const float*)d_in[8];
    const float* en_b = (const float*)d_in[9];
    const float* ln_g = (const float*)d_in[10];
    const float* ln_b = (const float*)d_in[11];

    float* out_final = (float*)d_out;
    float* attn_out  = out_final + (long long)BATCH * L_SEQ * D_MODEL;

    const long long MD = (long long)BATCH * L_SEQ * D_MODEL;   // 4,194,304
    const long long WN = (long long)D_MODEL * D_MODEL;         // 1,048,576

    float* EB = (float*)d_ws;                                  // [B,L,L] fp32
    float* EP = EB + (long long)BATCH * L_SEQ * L_SEQ;         // MD fp32 (also OUT)
    unsigned short* Xh   = (unsigned short*)(EP + MD);
    unsigned short* Qh   = Xh + MD;
    unsigned short* Kh   = Qh + MD;
    unsigned short* Vf   = Kh + MD;
    unsigned short* Vt   = Vf + MD;
    unsigned short* EFh  = Vt + MD;
    unsigned short* CTXh = EFh + MD;
    unsigned short* wqh  = CTXh + MD;
    unsigned short* wkh  = wqh + WN;
    unsigned short* wvh  = wkh + WN;
    unsigned short* eph  = wvh + WN;
    unsigned short* woh  = eph + WN;
    float* ebmax = (float*)(woh + WN);                         // B*L
    float* qn    = ebmax + (long long)BATCH * L_SEQ;           // B*H*L
    float* kn    = qn + (long long)BATCH * NUM_HEADS * L_SEQ;  // B*H*L
    float* kmax  = kn + (long long)BATCH * NUM_HEADS * L_SEQ;  // B*H
    float* OUT = EP;                                           // EP dead after ln

    const int M = BATCH * L_SEQ;                               // 4096
    dim3 blk(256);

    cvt6<<<dim3((unsigned)(MD / 1024), 6), blk, 0, stream>>>(
        x, wq, wk, wv, ep_w, wo_w, Xh, wqh, wkh, wvh, eph, woh,
        MD, WN, WN, WN, WN, WN);

    proj_gemm<<<dim3(D_MODEL / 128, M / 128, 4), blk, 0, stream>>>(
        Xh, wqh, wkh, wvh, eph, ep_b, Qh, Kh, Vf, EP);

    ln_rows<<<dim3(M), blk, 0, stream>>>(EP, nullptr, en_g, en_b, nullptr, EFh);

    gemm_bf16<<<dim3(L_SEQ / 128, L_SEQ / 128, BATCH), blk, 0, stream>>>(
        EFh, EFh, nullptr, EB, nullptr, L_SEQ, D_MODEL,
        (long long)L_SEQ * D_MODEL, (long long)L_SEQ * D_MODEL,
        (long long)L_SEQ * L_SEQ);

    qk_stats<<<dim3(L_SEQ / 64, NUM_HEADS, BATCH), blk, 0, stream>>>(Qh, Kh, qn, kn);
    kmax_red<<<dim3(BATCH * NUM_HEADS), blk, 0, stream>>>(kn, kmax);
    eb_rowmax<<<dim3(M), blk, 0, stream>>>(EB, ebmax);

    transpose_v<<<dim3(L_SEQ / 64, NUM_HEADS, BATCH), blk, 0, stream>>>(Vf, Vt);

    attn_mfma<<<dim3(L_SEQ / 64, NUM_HEADS, BATCH), blk, 0, stream>>>(
        Qh, Kh, Vt, EB, ebmax, qn, kmax, attn_out, CTXh);

    gemm_bf16<<<dim3(D_MODEL / 128, M / 128, 1), blk, 0, stream>>>(
        CTXh, woh, wo_b, OUT, nullptr, D_MODEL, D_MODEL, 0, 0, 0);

    ln_rows<<<dim3(M), blk, 0, stream>>>(OUT, x, ln_g, ln_b, out_final, nullptr);
}

// Round 7
// 789.651 us; speedup vs baseline: 1.3800x; 1.1332x over previous
//
#include <hip/hip_runtime.h>
#include <math.h>

#define D_MODEL 1024
#define NUM_HEADS 16
#define DK 64
#define L_SEQ 2048
#define BATCH 2
#define LN_EPS 1e-5f
#define ENERGY_SCALE 0.1f

typedef __attribute__((ext_vector_type(8))) short short8;
typedef __attribute__((ext_vector_type(4))) float f32x4;

__device__ __forceinline__ float waveReduceSum(float v) {
#pragma unroll
    for (int off = 32; off > 0; off >>= 1) v += __shfl_xor(v, off, 64);
    return v;
}

__device__ __forceinline__ unsigned short f2bf(float f) {
    unsigned int u = __float_as_uint(f);
    u += 0x7fff + ((u >> 16) & 1);          // round-to-nearest-even
    return (unsigned short)(u >> 16);
}
__device__ __forceinline__ float bf2f(unsigned short u) {
    return __uint_as_float((unsigned int)u << 16);
}

// ---------------- fp32 -> bf16 convert, 6 matrices in one launch ----------------
__global__ __launch_bounds__(256) void cvt6(
    const float* s0, const float* s1, const float* s2,
    const float* s3, const float* s4, const float* s5,
    unsigned short* d0, unsigned short* d1, unsigned short* d2,
    unsigned short* d3, unsigned short* d4, unsigned short* d5,
    long long n0, long long n1, long long n2, long long n3, long long n4, long long n5)
{
    const float* s; unsigned short* d; long long n;
    switch (blockIdx.y) {
        case 0: s = s0; d = d0; n = n0; break;
        case 1: s = s1; d = d1; n = n1; break;
        case 2: s = s2; d = d2; n = n2; break;
        case 3: s = s3; d = d3; n = n3; break;
        case 4: s = s4; d = d4; n = n4; break;
        default: s = s5; d = d5; n = n5; break;
    }
    long long i = ((long long)blockIdx.x * 256 + threadIdx.x) * 4;
    if (i >= n) return;
    float4 v = *(const float4*)(s + i);
    ushort4 o;
    o.x = f2bf(v.x); o.y = f2bf(v.y); o.z = f2bf(v.z); o.w = f2bf(v.w);
    *(ushort4*)(d + i) = o;
}

// ---------------- bf16 MFMA GEMM (verified round-3 version) ----------------
__global__ __launch_bounds__(256) void gemm_bf16(
    const unsigned short* __restrict__ A, const unsigned short* __restrict__ B,
    const float* __restrict__ bias, float* __restrict__ Cf, unsigned short* __restrict__ Ch,
    int N, int K, long long sA, long long sB, long long sC)
{
    A += (long long)blockIdx.z * sA;
    B += (long long)blockIdx.z * sB;
    __shared__ unsigned short As[128 * 72];
    __shared__ unsigned short Bs[128 * 72];
    const int tid = threadIdx.x;
    const int lane = tid & 63, w = tid >> 6;
    const int quad = lane >> 4, col = lane & 15;
    const int wm = w & 1, wn = w >> 1;
    const int row0 = blockIdx.y * 128, col0 = blockIdx.x * 128;

    f32x4 acc[4][4];
#pragma unroll
    for (int mt = 0; mt < 4; mt++)
#pragma unroll
        for (int nt = 0; nt < 4; nt++) acc[mt][nt] = (f32x4){0.f, 0.f, 0.f, 0.f};

    for (int k0 = 0; k0 < K; k0 += 64) {
        __syncthreads();
#pragma unroll
        for (int p = 0; p < 4; p++) {
            int u = tid + p * 256;
            int r = u >> 3;
            int c = (u & 7) * 8;
            *(uint4*)(As + r * 72 + c) = *(const uint4*)(A + (long long)(row0 + r) * K + k0 + c);
            *(uint4*)(Bs + r * 72 + c) = *(const uint4*)(B + (long long)(col0 + r) * K + k0 + c);
        }
        __syncthreads();
#pragma unroll
        for (int kc = 0; kc < 2; kc++) {
            short8 af[4], bfr[4];
#pragma unroll
            for (int mt = 0; mt < 4; mt++)
                af[mt] = *(const short8*)(As + (wm * 64 + mt * 16 + col) * 72 + quad * 8 + kc * 32);
#pragma unroll
            for (int nt = 0; nt < 4; nt++)
                bfr[nt] = *(const short8*)(Bs + (wn * 64 + nt * 16 + col) * 72 + quad * 8 + kc * 32);
#pragma unroll
            for (int mt = 0; mt < 4; mt++)
#pragma unroll
                for (int nt = 0; nt < 4; nt++)
                    acc[mt][nt] = __builtin_amdgcn_mfma_f32_16x16x32_bf16(af[mt], bfr[nt], acc[mt][nt], 0, 0, 0);
        }
    }

#pragma unroll
    for (int mt = 0; mt < 4; mt++)
#pragma unroll
        for (int nt = 0; nt < 4; nt++)
#pragma unroll
            for (int reg = 0; reg < 4; reg++) {
                long long row = row0 + wm * 64 + mt * 16 + quad * 4 + reg;
                int c = col0 + wn * 64 + nt * 16 + col;
                float v = acc[mt][nt][reg];
                if (bias) v += bias[c];
                if (Cf) Cf[blockIdx.z * sC + row * N + c] = v;
                else    Ch[blockIdx.z * sC + row * N + c] = f2bf(v);
            }
}

// ---------------- fused projections (verified round-3 version) ----------------
__global__ __launch_bounds__(256) void proj_gemm(
    const unsigned short* __restrict__ Xh,
    const unsigned short* __restrict__ wqh, const unsigned short* __restrict__ wkh,
    const unsigned short* __restrict__ wvh, const unsigned short* __restrict__ eph,
    const float* __restrict__ ep_b,
    unsigned short* __restrict__ Qh, unsigned short* __restrict__ Kh,
    unsigned short* __restrict__ Vf, float* __restrict__ EP)
{
    const unsigned short* B;
    switch (blockIdx.z) {
        case 0: B = wqh; break;
        case 1: B = wkh; break;
        case 2: B = wvh; break;
        default: B = eph; break;
    }
    __shared__ unsigned short As[128 * 72];
    __shared__ unsigned short Bs[128 * 72];
    const int tid = threadIdx.x;
    const int lane = tid & 63, w = tid >> 6;
    const int quad = lane >> 4, col = lane & 15;
    const int wm = w & 1, wn = w >> 1;
    const int row0 = blockIdx.y * 128, col0 = blockIdx.x * 128;
    const int K = D_MODEL, N = D_MODEL;

    f32x4 acc[4][4];
#pragma unroll
    for (int mt = 0; mt < 4; mt++)
#pragma unroll
        for (int nt = 0; nt < 4; nt++) acc[mt][nt] = (f32x4){0.f, 0.f, 0.f, 0.f};

    for (int k0 = 0; k0 < K; k0 += 64) {
        __syncthreads();
#pragma unroll
        for (int p = 0; p < 4; p++) {
            int u = tid + p * 256;
            int r = u >> 3;
            int c = (u & 7) * 8;
            *(uint4*)(As + r * 72 + c) = *(const uint4*)(Xh + (long long)(row0 + r) * K + k0 + c);
            *(uint4*)(Bs + r * 72 + c) = *(const uint4*)(B + (long long)(col0 + r) * K + k0 + c);
        }
        __syncthreads();
#pragma unroll
        for (int kc = 0; kc < 2; kc++) {
            short8 af[4], bfr[4];
#pragma unroll
            for (int mt = 0; mt < 4; mt++)
                af[mt] = *(const short8*)(As + (wm * 64 + mt * 16 + col) * 72 + quad * 8 + kc * 32);
#pragma unroll
            for (int nt = 0; nt < 4; nt++)
                bfr[nt] = *(const short8*)(Bs + (wn * 64 + nt * 16 + col) * 72 + quad * 8 + kc * 32);
#pragma unroll
            for (int mt = 0; mt < 4; mt++)
#pragma unroll
                for (int nt = 0; nt < 4; nt++)
                    acc[mt][nt] = __builtin_amdgcn_mfma_f32_16x16x32_bf16(af[mt], bfr[nt], acc[mt][nt], 0, 0, 0);
        }
    }

    unsigned short* Hout = (blockIdx.z == 0) ? Qh : (blockIdx.z == 1) ? Kh : Vf;
#pragma unroll
    for (int mt = 0; mt < 4; mt++)
#pragma unroll
        for (int nt = 0; nt < 4; nt++)
#pragma unroll
            for (int reg = 0; reg < 4; reg++) {
                long long row = row0 + wm * 64 + mt * 16 + quad * 4 + reg;
                int c = col0 + wn * 64 + nt * 16 + col;
                float v = acc[mt][nt][reg];
                if (blockIdx.z == 3) EP[row * N + c] = v + ep_b[c];
                else                 Hout[row * N + c] = f2bf(v);
            }
}

// ---------------- LayerNorm rows ----------------
__global__ __launch_bounds__(256) void ln_rows(
    const float* __restrict__ in, const float* __restrict__ res,
    const float* __restrict__ g, const float* __restrict__ bta,
    float* __restrict__ outf, unsigned short* __restrict__ outh)
{
    const long long row = blockIdx.x;
    const float* ip = in + row * D_MODEL;
    const float* rp = res ? res + row * D_MODEL : nullptr;
    const int tid = threadIdx.x;
    float vals[4];
    float s = 0.f, ss = 0.f;
#pragma unroll
    for (int j = 0; j < 4; j++) {
        int idx = tid + j * 256;
        float v = ip[idx];
        if (rp) v += rp[idx];
        vals[j] = v; s += v; ss += v * v;
    }
    __shared__ float sred[4], ssred[4];
    s = waveReduceSum(s); ss = waveReduceSum(ss);
    int wave = tid >> 6, lane = tid & 63;
    if (lane == 0) { sred[wave] = s; ssred[wave] = ss; }
    __syncthreads();
    float ts = sred[0] + sred[1] + sred[2] + sred[3];
    float tss = ssred[0] + ssred[1] + ssred[2] + ssred[3];
    float mu = ts * (1.f / D_MODEL);
    float var = tss * (1.f / D_MODEL) - mu * mu;
    float rs = rsqrtf(var + LN_EPS);
#pragma unroll
    for (int j = 0; j < 4; j++) {
        int idx = tid + j * 256;
        float o = (vals[j] - mu) * rs * g[idx] + bta[idx];
        if (outf) outf[row * D_MODEL + idx] = o;
        else      outh[row * D_MODEL + idx] = f2bf(o);
    }
}

// ---------------- V transpose ----------------
__global__ __launch_bounds__(256) void transpose_v(
    const unsigned short* __restrict__ V, unsigned short* __restrict__ Vt)
{
    const int m0 = blockIdx.x * 64, h = blockIdx.y, b = blockIdx.z;
    __shared__ unsigned int t[64][65];
    const int tid = threadIdx.x;
    {
        int r = tid >> 4, c4 = (tid & 15) * 4;
#pragma unroll
        for (int i = 0; i < 4; i++) {
            int row = r + i * 16;
            ushort4 v = *(const ushort4*)(V + ((long long)b * L_SEQ + m0 + row) * D_MODEL + h * DK + c4);
            t[row][c4] = v.x; t[row][c4 + 1] = v.y; t[row][c4 + 2] = v.z; t[row][c4 + 3] = v.w;
        }
    }
    __syncthreads();
    const int lane = tid & 63, wv = tid >> 6;
#pragma unroll
    for (int i = 0; i < 16; i++) {
        int d = wv * 16 + i;
        Vt[(((long long)(b * NUM_HEADS + h)) * DK + d) * L_SEQ + m0 + lane] = (unsigned short)t[lane][d];
    }
}

// ---------------- stats: EB row max + per-64-tile max, one pass ----------------
__global__ __launch_bounds__(256) void eb_stats(
    const float* __restrict__ EB, float* __restrict__ ebmax, float* __restrict__ ebtmax)
{
    const long long row = blockIdx.x;                 // 0 .. B*L-1
    const float* p = EB + row * L_SEQ;
    const int tid = threadIdx.x;
    float4 a = *(const float4*)(p + tid * 8);
    float4 c = *(const float4*)(p + tid * 8 + 4);
    float m = fmaxf(fmaxf(fmaxf(a.x, a.y), fmaxf(a.z, a.w)),
                    fmaxf(fmaxf(c.x, c.y), fmaxf(c.z, c.w)));
    // tile max: 8 threads per 64-elem tile
    m = fmaxf(m, __shfl_xor(m, 1, 64));
    m = fmaxf(m, __shfl_xor(m, 2, 64));
    m = fmaxf(m, __shfl_xor(m, 4, 64));
    if ((tid & 7) == 0) ebtmax[row * 32 + (tid >> 3)] = m;
    // row max
    m = fmaxf(m, __shfl_xor(m, 8, 64));
    m = fmaxf(m, __shfl_xor(m, 16, 64));
    m = fmaxf(m, __shfl_xor(m, 32, 64));
    __shared__ float red[4];
    if ((tid & 63) == 0) red[tid >> 6] = m;
    __syncthreads();
    if (tid == 0)
        ebmax[row] = fmaxf(fmaxf(red[0], red[1]), fmaxf(red[2], red[3]));
}

// ---------------- stats: qn/kn per (b,h,l) ----------------
__global__ __launch_bounds__(256) void qk_stats(
    const unsigned short* __restrict__ Qh, const unsigned short* __restrict__ Kh,
    float* __restrict__ qn, float* __restrict__ kn)
{
    const int l0 = blockIdx.x * 64, h = blockIdx.y, b = blockIdx.z;
    const int tid = threadIdx.x;
    const int r = tid >> 2, p4 = (tid & 3) * 16;
    const unsigned short* q = Qh + ((long long)b * L_SEQ + l0 + r) * D_MODEL + h * DK + p4;
    const unsigned short* k = Kh + ((long long)b * L_SEQ + l0 + r) * D_MODEL + h * DK + p4;
    float sq = 0.f, sk = 0.f;
#pragma unroll
    for (int i = 0; i < 16; i++) {
        float qv = bf2f(q[i]); sq += qv * qv;
        float kv = bf2f(k[i]); sk += kv * kv;
    }
    sq += __shfl_xor(sq, 1, 64); sq += __shfl_xor(sq, 2, 64);
    sk += __shfl_xor(sk, 1, 64); sk += __shfl_xor(sk, 2, 64);
    if ((tid & 3) == 0) {
        long long idx = ((long long)(b * NUM_HEADS + h)) * L_SEQ + l0 + r;
        qn[idx] = sqrtf(sq);
        kn[idx] = sqrtf(sk);
    }
}

// ---------------- stats: per-(b,h) k-norm global + per-tile max ----------------
__global__ __launch_bounds__(256) void kstats2(
    const float* __restrict__ kn, float* __restrict__ kmax, float* __restrict__ ktmax)
{
    const long long bh = blockIdx.x;
    const float* p = kn + bh * L_SEQ;
    const int tid = threadIdx.x;
    float4 a = *(const float4*)(p + tid * 8);
    float4 c = *(const float4*)(p + tid * 8 + 4);
    float m = fmaxf(fmaxf(fmaxf(a.x, a.y), fmaxf(a.z, a.w)),
                    fmaxf(fmaxf(c.x, c.y), fmaxf(c.z, c.w)));
    m = fmaxf(m, __shfl_xor(m, 1, 64));
    m = fmaxf(m, __shfl_xor(m, 2, 64));
    m = fmaxf(m, __shfl_xor(m, 4, 64));
    if ((tid & 7) == 0) ktmax[bh * 32 + (tid >> 3)] = m;
    m = fmaxf(m, __shfl_xor(m, 8, 64));
    m = fmaxf(m, __shfl_xor(m, 16, 64));
    m = fmaxf(m, __shfl_xor(m, 32, 64));
    __shared__ float red[4];
    if ((tid & 63) == 0) red[tid >> 6] = m;
    __syncthreads();
    if (tid == 0)
        kmax[bh] = fmaxf(fmaxf(red[0], red[1]), fmaxf(red[2], red[3]));
}

// ---------------- skip mask: bit t set iff tile t provably negligible ----------------
// For all 64 rows of the block: 0.1*ebtmax + qn*ktmax/8 < Mhat(row) - 45
// => every p in tile < e^-40 (rowS >= e^-overshoot, overshoot << 45). Writing 0 there
// incurs absmax error <= 4e-18 vs threshold 9.6e-2. Adversarial inputs: mask=0, full compute.
__global__ __launch_bounds__(64) void skip_mask(
    const float* __restrict__ ebmax, const float* __restrict__ ebtmax,
    const float* __restrict__ qn, const float* __restrict__ kmax,
    const float* __restrict__ ktmax, unsigned int* __restrict__ skipm)
{
    const int l0 = blockIdx.x * 64, h = blockIdx.y, b = blockIdx.z;
    const int tid = threadIdx.x;
    const int row = l0 + tid;
    const int bh = b * NUM_HEADS + h;
    float q = qn[(long long)bh * L_SEQ + row];
    float Mh = ENERGY_SCALE * ebmax[(long long)b * L_SEQ + row] + q * kmax[bh] * 0.125f + 0.02f;
    const float* ebt = ebtmax + ((long long)b * L_SEQ + row) * 32;
    const float* ktm = ktmax + bh * 32;
    unsigned int m = 0;
    for (int t = 0; t < 32; t++) {
        float ub = ENERGY_SCALE * ebt[t] + q * ktm[t] * 0.125f;
        unsigned long long bal = __ballot(ub < Mh - 45.0f);
        if (bal == ~0ull) m |= (1u << t);
    }
    if (tid == 0) skipm[bh * 32 + blockIdx.x] = m;
}

// ---------------- MFMA attention: single sweep + provable tile skip ----------------
__global__ __launch_bounds__(256) void attn_mfma(
    const unsigned short* __restrict__ Qh, const unsigned short* __restrict__ Kh,
    const unsigned short* __restrict__ Vt, const float* __restrict__ EB,
    const float* __restrict__ ebmax, const float* __restrict__ qn,
    const float* __restrict__ kmax, const unsigned int* __restrict__ skipm,
    float* __restrict__ attn_out, unsigned short* __restrict__ CTXh)
{
    __shared__ unsigned short Ks[64 * 72];
    __shared__ unsigned short Vts[64 * 72];
    __shared__ unsigned short Ps[4 * 16 * 72];

    const int tid = threadIdx.x;
    const int lane = tid & 63, w = tid >> 6;
    const int quad = lane >> 4, col = lane & 15;
    const int l0 = blockIdx.x * 64;
    const int h = blockIdx.y, b = blockIdx.z;

    short8 aq[2];
    {
        const unsigned short* qrow = Qh + ((long long)b * L_SEQ + l0 + w * 16 + col) * D_MODEL + h * DK;
        aq[0] = *(const short8*)(qrow + quad * 8);
        aq[1] = *(const short8*)(qrow + 32 + quad * 8);
    }

    float Mhat[4];
    {
        const float km = kmax[b * NUM_HEADS + h];
#pragma unroll
        for (int reg = 0; reg < 4; reg++) {
            int row = l0 + w * 16 + quad * 4 + reg;
            float qb = qn[((long long)(b * NUM_HEADS + h)) * L_SEQ + row];
            Mhat[reg] = ENERGY_SCALE * ebmax[(long long)b * L_SEQ + row] +
                        qb * km * 0.125f + 0.02f;
        }
    }

    const unsigned int sm = skipm[(b * NUM_HEADS + h) * 32 + blockIdx.x];

    const float* ebp = EB + ((long long)b * L_SEQ + l0 + w * 16 + quad * 4) * L_SEQ + col;
    const unsigned short* kbase = Kh + ((long long)b * L_SEQ) * D_MODEL + h * DK;
    const unsigned short* vbase = Vt + ((long long)(b * NUM_HEADS + h)) * DK * L_SEQ;

    const int sr = tid >> 2, sc0 = (tid & 3) * 16;

    // ---- pass 1: rowS over active tiles only ----
    float rowSacc[4] = {0.f, 0.f, 0.f, 0.f};
    for (int t = 0; t < 32; t++) {
        if (sm & (1u << t)) continue;
        const int m0 = t * 64;
        __syncthreads();
        *(uint4*)(Ks + sr * 72 + sc0)     = *(const uint4*)(kbase + (long long)(m0 + sr) * D_MODEL + sc0);
        *(uint4*)(Ks + sr * 72 + sc0 + 8) = *(const uint4*)(kbase + (long long)(m0 + sr) * D_MODEL + sc0 + 8);
        __syncthreads();

        f32x4 acc[4];
#pragma unroll
        for (int nt = 0; nt < 4; nt++) acc[nt] = (f32x4){0.f, 0.f, 0.f, 0.f};
#pragma unroll
        for (int nt = 0; nt < 4; nt++)
#pragma unroll
            for (int kc = 0; kc < 2; kc++) {
                short8 bk = *(const short8*)(Ks + (nt * 16 + col) * 72 + quad * 8 + kc * 32);
                acc[nt] = __builtin_amdgcn_mfma_f32_16x16x32_bf16(aq[kc], bk, acc[nt], 0, 0, 0);
            }
#pragma unroll
        for (int nt = 0; nt < 4; nt++)
#pragma unroll
            for (int reg = 0; reg < 4; reg++) {
                float s = acc[nt][reg] * 0.125f + ENERGY_SCALE * ebp[(long long)reg * L_SEQ + m0 + nt * 16];
                rowSacc[reg] += __expf(s - Mhat[reg]);
            }
    }

    float invS[4];
#pragma unroll
    for (int reg = 0; reg < 4; reg++) {
        float v = rowSacc[reg];
#pragma unroll
        for (int off = 8; off > 0; off >>= 1) v += __shfl_xor(v, off, 64);
        invS[reg] = 1.f / v;
    }

    // ---- pass 2: write attn (zeros for skipped tiles), ctx = P V ----
    f32x4 ctx[4];
#pragma unroll
    for (int nt = 0; nt < 4; nt++) ctx[nt] = (f32x4){0.f, 0.f, 0.f, 0.f};

    unsigned short* Psw = Ps + w * 16 * 72;
    float* aob = attn_out + (((long long)(b * NUM_HEADS + h)) * L_SEQ + l0 + w * 16 + quad * 4) * L_SEQ + col;

    for (int t = 0; t < 32; t++) {
        const int m0 = t * 64;
        if (sm & (1u << t)) {
#pragma unroll
            for (int nt = 0; nt < 4; nt++)
#pragma unroll
                for (int reg = 0; reg < 4; reg++)
                    aob[(long long)reg * L_SEQ + m0 + nt * 16] = 0.f;
            continue;
        }
        __syncthreads();
        *(uint4*)(Ks + sr * 72 + sc0)      = *(const uint4*)(kbase + (long long)(m0 + sr) * D_MODEL + sc0);
        *(uint4*)(Ks + sr * 72 + sc0 + 8)  = *(const uint4*)(kbase + (long long)(m0 + sr) * D_MODEL + sc0 + 8);
        *(uint4*)(Vts + sr * 72 + sc0)     = *(const uint4*)(vbase + (long long)sr * L_SEQ + m0 + sc0);
        *(uint4*)(Vts + sr * 72 + sc0 + 8) = *(const uint4*)(vbase + (long long)sr * L_SEQ + m0 + sc0 + 8);
        __syncthreads();

        f32x4 acc[4];
#pragma unroll
        for (int nt = 0; nt < 4; nt++) acc[nt] = (f32x4){0.f, 0.f, 0.f, 0.f};
#pragma unroll
        for (int nt = 0; nt < 4; nt++)
#pragma unroll
            for (int kc = 0; kc < 2; kc++) {
                short8 bk = *(const short8*)(Ks + (nt * 16 + col) * 72 + quad * 8 + kc * 32);
                acc[nt] = __builtin_amdgcn_mfma_f32_16x16x32_bf16(aq[kc], bk, acc[nt], 0, 0, 0);
            }

#pragma unroll
        for (int nt = 0; nt < 4; nt++)
#pragma unroll
            for (int reg = 0; reg < 4; reg++) {
                float s = acc[nt][reg] * 0.125f + ENERGY_SCALE * ebp[(long long)reg * L_SEQ + m0 + nt * 16];
                float p = __expf(s - Mhat[reg]) * invS[reg];
                aob[(long long)reg * L_SEQ + m0 + nt * 16] = p;
                Psw[(quad * 4 + reg) * 72 + nt * 16 + col] = f2bf(p);
            }

        short8 ap[2];
#pragma unroll
        for (int kc = 0; kc < 2; kc++)
            ap[kc] = *(const short8*)(Psw + col * 72 + quad * 8 + kc * 32);
#pragma unroll
        for (int nt = 0; nt < 4; nt++)
#pragma unroll
            for (int kc = 0; kc < 2; kc++) {
                short8 bv = *(const short8*)(Vts + (nt * 16 + col) * 72 + quad * 8 + kc * 32);
                ctx[nt] = __builtin_amdgcn_mfma_f32_16x16x32_bf16(ap[kc], bv, ctx[nt], 0, 0, 0);
            }
    }

#pragma unroll
    for (int nt = 0; nt < 4; nt++)
#pragma unroll
        for (int reg = 0; reg < 4; reg++)
            CTXh[((long long)b * L_SEQ + l0 + w * 16 + quad * 4 + reg) * D_MODEL + h * DK + nt * 16 + col] =
                f2bf(ctx[nt][reg]);
}

extern "C" void kernel_launch(void* const* d_in, const int* in_sizes, int n_in,
                              void* d_out, int out_size, void* d_ws, size_t ws_size,
                              hipStream_t stream) {
    const float* x    = (const float*)d_in[0];
    const float* wq   = (const float*)d_in[1];
    const float* wk   = (const float*)d_in[2];
    const float* wv   = (const float*)d_in[3];
    const float* wo_w = (const float*)d_in[4];
    const float* wo_b = (const float*)d_in[5];
    const float* ep_w = (const float*)d_in[6];
    const float* ep_b = (const float*)d_in[7];
    const float* en_g = (const float*)d_in[8];
    const float* en_b = (const float*)d_in[9];
    const float* ln_g = (const float*)d_in[10];
    const float* ln_b = (const float*)d_in[11];

    float* out_final = (float*)d_out;
    float* attn_out  = out_final + (long long)BATCH * L_SEQ * D_MODEL;

    const long long MD = (long long)BATCH * L_SEQ * D_MODEL;   // 4,194,304
    const long long WN = (long long)D_MODEL * D_MODEL;         // 1,048,576
    const long long BH = (long long)BATCH * NUM_HEADS;

    float* EB = (float*)d_ws;                                  // [B,L,L] fp32
    float* EP = EB + (long long)BATCH * L_SEQ * L_SEQ;         // MD fp32 (also OUT)
    unsigned short* Xh   = (unsigned short*)(EP + MD);
    unsigned short* Qh   = Xh + MD;
    unsigned short* Kh   = Qh + MD;
    unsigned short* Vf   = Kh + MD;
    unsigned short* Vt   = Vf + MD;
    unsigned short* EFh  = Vt + MD;
    unsigned short* CTXh = EFh + MD;
    unsigned short* wqh  = CTXh + MD;
    unsigned short* wkh  = wqh + WN;
    unsigned short* wvh  = wkh + WN;
    unsigned short* eph  = wvh + WN;
    unsigned short* woh  = eph + WN;
    float* ebmax  = (float*)(woh + WN);                        // B*L
    float* qn     = ebmax + (long long)BATCH * L_SEQ;          // B*H*L
    float* kn     = qn + BH * L_SEQ;                           // B*H*L
    float* kmax   = kn + BH * L_SEQ;                           // B*H
    float* ktmax  = kmax + BH;                                 // B*H*32
    float* ebtmax = ktmax + BH * 32;                           // B*L*32
    unsigned int* skipm = (unsigned int*)(ebtmax + (long long)BATCH * L_SEQ * 32); // B*H*32
    float* OUT = EP;                                           // EP dead after ln

    const int M = BATCH * L_SEQ;                               // 4096
    dim3 blk(256);

    cvt6<<<dim3((unsigned)(MD / 1024), 6), blk, 0, stream>>>(
        x, wq, wk, wv, ep_w, wo_w, Xh, wqh, wkh, wvh, eph, woh,
        MD, WN, WN, WN, WN, WN);

    proj_gemm<<<dim3(D_MODEL / 128, M / 128, 4), blk, 0, stream>>>(
        Xh, wqh, wkh, wvh, eph, ep_b, Qh, Kh, Vf, EP);

    ln_rows<<<dim3(M), blk, 0, stream>>>(EP, nullptr, en_g, en_b, nullptr, EFh);

    gemm_bf16<<<dim3(L_SEQ / 128, L_SEQ / 128, BATCH), blk, 0, stream>>>(
        EFh, EFh, nullptr, EB, nullptr, L_SEQ, D_MODEL,
        (long long)L_SEQ * D_MODEL, (long long)L_SEQ * D_MODEL,
        (long long)L_SEQ * L_SEQ);

    qk_stats<<<dim3(L_SEQ / 64, NUM_HEADS, BATCH), blk, 0, stream>>>(Qh, Kh, qn, kn);
    kstats2<<<dim3((unsigned)BH), blk, 0, stream>>>(kn, kmax, ktmax);
    eb_stats<<<dim3(M), blk, 0, stream>>>(EB, ebmax, ebtmax);
    skip_mask<<<dim3(L_SEQ / 64, NUM_HEADS, BATCH), dim3(64), 0, stream>>>(
        ebmax, ebtmax, qn, kmax, ktmax, skipm);

    transpose_v<<<dim3(L_SEQ / 64, NUM_HEADS, BATCH), blk, 0, stream>>>(Vf, Vt);

    attn_mfma<<<dim3(L_SEQ / 64, NUM_HEADS, BATCH), blk, 0, stream>>>(
        Qh, Kh, Vt, EB, ebmax, qn, kmax, skipm, attn_out, CTXh);

    gemm_bf16<<<dim3(D_MODEL / 128, M / 128, 1), blk, 0, stream>>>(
        CTXh, woh, wo_b, OUT, nullptr, D_MODEL, D_MODEL, 0, 0, 0);

    ln_rows<<<dim3(M), blk, 0, stream>>>(OUT, x, ln_g, ln_b, out_final, nullptr);
}

// Round 8
// 783.658 us; speedup vs baseline: 1.3905x; 1.0076x over previous
//
#include <hip/hip_runtime.h>
#include <math.h>

#define D_MODEL 1024
#define NUM_HEADS 16
#define DK 64
#define L_SEQ 2048
#define BATCH 2
#define LN_EPS 1e-5f
#define ENERGY_SCALE 0.1f

typedef __attribute__((ext_vector_type(8))) short short8;
typedef __attribute__((ext_vector_type(4))) float f32x4;
typedef __attribute__((address_space(1))) const unsigned int gas_u32;
typedef __attribute__((address_space(3))) unsigned int las_u32;

__device__ __forceinline__ float waveReduceSum(float v) {
#pragma unroll
    for (int off = 32; off > 0; off >>= 1) v += __shfl_xor(v, off, 64);
    return v;
}

__device__ __forceinline__ unsigned short f2bf(float f) {
    unsigned int u = __float_as_uint(f);
    u += 0x7fff + ((u >> 16) & 1);          // round-to-nearest-even
    return (unsigned short)(u >> 16);
}
__device__ __forceinline__ float bf2f(unsigned short u) {
    return __uint_as_float((unsigned int)u << 16);
}

// ---------------- fp32 -> bf16 convert, 6 matrices in one launch ----------------
__global__ __launch_bounds__(256) void cvt6(
    const float* s0, const float* s1, const float* s2,
    const float* s3, const float* s4, const float* s5,
    unsigned short* d0, unsigned short* d1, unsigned short* d2,
    unsigned short* d3, unsigned short* d4, unsigned short* d5,
    long long n0, long long n1, long long n2, long long n3, long long n4, long long n5)
{
    const float* s; unsigned short* d; long long n;
    switch (blockIdx.y) {
        case 0: s = s0; d = d0; n = n0; break;
        case 1: s = s1; d = d1; n = n1; break;
        case 2: s = s2; d = d2; n = n2; break;
        case 3: s = s3; d = d3; n = n3; break;
        case 4: s = s4; d = d4; n = n4; break;
        default: s = s5; d = d5; n = n5; break;
    }
    long long i = ((long long)blockIdx.x * 256 + threadIdx.x) * 4;
    if (i >= n) return;
    float4 v = *(const float4*)(s + i);
    ushort4 o;
    o.x = f2bf(v.x); o.y = f2bf(v.y); o.z = f2bf(v.z); o.w = f2bf(v.w);
    *(ushort4*)(d + i) = o;
}

// ---------------- bf16 MFMA GEMM with global_load_lds (m97-style) ----------------
// C[M,N] = A[M,K] * B[N,K]^T (+bias); 128x128 tile, BK=64, 4 waves (2x2).
// LDS tiles 128x64 bf16 unpadded; chunk-XOR swizzle (c' = c ^ (row&7)) applied on
// the global source so ds_read_b128 fragments are bank-conflict-free.
__global__ __launch_bounds__(256) void gemm_bf16(
    const unsigned short* __restrict__ A, const unsigned short* __restrict__ B,
    const float* __restrict__ bias, float* __restrict__ Cf, unsigned short* __restrict__ Ch,
    int N, int K, long long sA, long long sB, long long sC)
{
    A += (long long)blockIdx.z * sA;
    B += (long long)blockIdx.z * sB;
    __shared__ unsigned short As[128 * 64];
    __shared__ unsigned short Bs[128 * 64];
    const int tid = threadIdx.x;
    const int lane = tid & 63, w = tid >> 6;
    const int quad = lane >> 4, col = lane & 15;
    const int wm = w & 1, wn = w >> 1;
    const int row0 = blockIdx.y * 128, col0 = blockIdx.x * 128;

    // staging lane mapping: lane = 8*lr + lc -> row +lr, LDS chunk lc, global chunk lc^lr
    const int lr = lane >> 3, lc = lane & 7;
    const int gcs = (lc ^ lr) * 8;                 // swizzled source column (shorts)

    f32x4 acc[4][4];
#pragma unroll
    for (int mt = 0; mt < 4; mt++)
#pragma unroll
        for (int nt = 0; nt < 4; nt++) acc[mt][nt] = (f32x4){0.f, 0.f, 0.f, 0.f};

    for (int k0 = 0; k0 < K; k0 += 64) {
        __syncthreads();
#pragma unroll
        for (int p = 0; p < 4; p++) {
            const int rb = w * 32 + p * 8;         // 8-row group base
            __builtin_amdgcn_global_load_lds(
                (gas_u32*)(A + (long long)(row0 + rb + lr) * K + k0 + gcs),
                (las_u32*)(As + rb * 64), 16, 0, 0);
            __builtin_amdgcn_global_load_lds(
                (gas_u32*)(B + (long long)(col0 + rb + lr) * K + k0 + gcs),
                (las_u32*)(Bs + rb * 64), 16, 0, 0);
        }
        __syncthreads();
#pragma unroll
        for (int kc = 0; kc < 2; kc++) {
            const int csw = ((quad + 4 * kc) ^ (col & 7)) * 8;
            short8 af[4], bfr[4];
#pragma unroll
            for (int mt = 0; mt < 4; mt++)
                af[mt] = *(const short8*)(As + (wm * 64 + mt * 16 + col) * 64 + csw);
#pragma unroll
            for (int nt = 0; nt < 4; nt++)
                bfr[nt] = *(const short8*)(Bs + (wn * 64 + nt * 16 + col) * 64 + csw);
#pragma unroll
            for (int mt = 0; mt < 4; mt++)
#pragma unroll
                for (int nt = 0; nt < 4; nt++)
                    acc[mt][nt] = __builtin_amdgcn_mfma_f32_16x16x32_bf16(af[mt], bfr[nt], acc[mt][nt], 0, 0, 0);
        }
    }

#pragma unroll
    for (int mt = 0; mt < 4; mt++)
#pragma unroll
        for (int nt = 0; nt < 4; nt++)
#pragma unroll
            for (int reg = 0; reg < 4; reg++) {
                long long row = row0 + wm * 64 + mt * 16 + quad * 4 + reg;
                int c = col0 + wn * 64 + nt * 16 + col;
                float v = acc[mt][nt][reg];
                if (bias) v += bias[c];
                if (Cf) Cf[blockIdx.z * sC + row * N + c] = v;
                else    Ch[blockIdx.z * sC + row * N + c] = f2bf(v);
            }
}

// ---------------- fused projections with global_load_lds ----------------
__global__ __launch_bounds__(256) void proj_gemm(
    const unsigned short* __restrict__ Xh,
    const unsigned short* __restrict__ wqh, const unsigned short* __restrict__ wkh,
    const unsigned short* __restrict__ wvh, const unsigned short* __restrict__ eph,
    const float* __restrict__ ep_b,
    unsigned short* __restrict__ Qh, unsigned short* __restrict__ Kh,
    unsigned short* __restrict__ Vf, float* __restrict__ EP)
{
    const unsigned short* B;
    switch (blockIdx.z) {
        case 0: B = wqh; break;
        case 1: B = wkh; break;
        case 2: B = wvh; break;
        default: B = eph; break;
    }
    __shared__ unsigned short As[128 * 64];
    __shared__ unsigned short Bs[128 * 64];
    const int tid = threadIdx.x;
    const int lane = tid & 63, w = tid >> 6;
    const int quad = lane >> 4, col = lane & 15;
    const int wm = w & 1, wn = w >> 1;
    const int row0 = blockIdx.y * 128, col0 = blockIdx.x * 128;
    const int K = D_MODEL, N = D_MODEL;

    const int lr = lane >> 3, lc = lane & 7;
    const int gcs = (lc ^ lr) * 8;

    f32x4 acc[4][4];
#pragma unroll
    for (int mt = 0; mt < 4; mt++)
#pragma unroll
        for (int nt = 0; nt < 4; nt++) acc[mt][nt] = (f32x4){0.f, 0.f, 0.f, 0.f};

    for (int k0 = 0; k0 < K; k0 += 64) {
        __syncthreads();
#pragma unroll
        for (int p = 0; p < 4; p++) {
            const int rb = w * 32 + p * 8;
            __builtin_amdgcn_global_load_lds(
                (gas_u32*)(Xh + (long long)(row0 + rb + lr) * K + k0 + gcs),
                (las_u32*)(As + rb * 64), 16, 0, 0);
            __builtin_amdgcn_global_load_lds(
                (gas_u32*)(B + (long long)(col0 + rb + lr) * K + k0 + gcs),
                (las_u32*)(Bs + rb * 64), 16, 0, 0);
        }
        __syncthreads();
#pragma unroll
        for (int kc = 0; kc < 2; kc++) {
            const int csw = ((quad + 4 * kc) ^ (col & 7)) * 8;
            short8 af[4], bfr[4];
#pragma unroll
            for (int mt = 0; mt < 4; mt++)
                af[mt] = *(const short8*)(As + (wm * 64 + mt * 16 + col) * 64 + csw);
#pragma unroll
            for (int nt = 0; nt < 4; nt++)
                bfr[nt] = *(const short8*)(Bs + (wn * 64 + nt * 16 + col) * 64 + csw);
#pragma unroll
            for (int mt = 0; mt < 4; mt++)
#pragma unroll
                for (int nt = 0; nt < 4; nt++)
                    acc[mt][nt] = __builtin_amdgcn_mfma_f32_16x16x32_bf16(af[mt], bfr[nt], acc[mt][nt], 0, 0, 0);
        }
    }

    unsigned short* Hout = (blockIdx.z == 0) ? Qh : (blockIdx.z == 1) ? Kh : Vf;
#pragma unroll
    for (int mt = 0; mt < 4; mt++)
#pragma unroll
        for (int nt = 0; nt < 4; nt++)
#pragma unroll
            for (int reg = 0; reg < 4; reg++) {
                long long row = row0 + wm * 64 + mt * 16 + quad * 4 + reg;
                int c = col0 + wn * 64 + nt * 16 + col;
                float v = acc[mt][nt][reg];
                if (blockIdx.z == 3) EP[row * N + c] = v + ep_b[c];
                else                 Hout[row * N + c] = f2bf(v);
            }
}

// ---------------- LayerNorm rows ----------------
__global__ __launch_bounds__(256) void ln_rows(
    const float* __restrict__ in, const float* __restrict__ res,
    const float* __restrict__ g, const float* __restrict__ bta,
    float* __restrict__ outf, unsigned short* __restrict__ outh)
{
    const long long row = blockIdx.x;
    const float* ip = in + row * D_MODEL;
    const float* rp = res ? res + row * D_MODEL : nullptr;
    const int tid = threadIdx.x;
    float vals[4];
    float s = 0.f, ss = 0.f;
#pragma unroll
    for (int j = 0; j < 4; j++) {
        int idx = tid + j * 256;
        float v = ip[idx];
        if (rp) v += rp[idx];
        vals[j] = v; s += v; ss += v * v;
    }
    __shared__ float sred[4], ssred[4];
    s = waveReduceSum(s); ss = waveReduceSum(ss);
    int wave = tid >> 6, lane = tid & 63;
    if (lane == 0) { sred[wave] = s; ssred[wave] = ss; }
    __syncthreads();
    float ts = sred[0] + sred[1] + sred[2] + sred[3];
    float tss = ssred[0] + ssred[1] + ssred[2] + ssred[3];
    float mu = ts * (1.f / D_MODEL);
    float var = tss * (1.f / D_MODEL) - mu * mu;
    float rs = rsqrtf(var + LN_EPS);
#pragma unroll
    for (int j = 0; j < 4; j++) {
        int idx = tid + j * 256;
        float o = (vals[j] - mu) * rs * g[idx] + bta[idx];
        if (outf) outf[row * D_MODEL + idx] = o;
        else      outh[row * D_MODEL + idx] = f2bf(o);
    }
}

// ---------------- V transpose ----------------
__global__ __launch_bounds__(256) void transpose_v(
    const unsigned short* __restrict__ V, unsigned short* __restrict__ Vt)
{
    const int m0 = blockIdx.x * 64, h = blockIdx.y, b = blockIdx.z;
    __shared__ unsigned int t[64][65];
    const int tid = threadIdx.x;
    {
        int r = tid >> 4, c4 = (tid & 15) * 4;
#pragma unroll
        for (int i = 0; i < 4; i++) {
            int row = r + i * 16;
            ushort4 v = *(const ushort4*)(V + ((long long)b * L_SEQ + m0 + row) * D_MODEL + h * DK + c4);
            t[row][c4] = v.x; t[row][c4 + 1] = v.y; t[row][c4 + 2] = v.z; t[row][c4 + 3] = v.w;
        }
    }
    __syncthreads();
    const int lane = tid & 63, wv = tid >> 6;
#pragma unroll
    for (int i = 0; i < 16; i++) {
        int d = wv * 16 + i;
        Vt[(((long long)(b * NUM_HEADS + h)) * DK + d) * L_SEQ + m0 + lane] = (unsigned short)t[lane][d];
    }
}

// ---------------- stats: EB row max + per-64-tile max, one pass ----------------
__global__ __launch_bounds__(256) void eb_stats(
    const float* __restrict__ EB, float* __restrict__ ebmax, float* __restrict__ ebtmax)
{
    const long long row = blockIdx.x;                 // 0 .. B*L-1
    const float* p = EB + row * L_SEQ;
    const int tid = threadIdx.x;
    float4 a = *(const float4*)(p + tid * 8);
    float4 c = *(const float4*)(p + tid * 8 + 4);
    float m = fmaxf(fmaxf(fmaxf(a.x, a.y), fmaxf(a.z, a.w)),
                    fmaxf(fmaxf(c.x, c.y), fmaxf(c.z, c.w)));
    m = fmaxf(m, __shfl_xor(m, 1, 64));
    m = fmaxf(m, __shfl_xor(m, 2, 64));
    m = fmaxf(m, __shfl_xor(m, 4, 64));
    if ((tid & 7) == 0) ebtmax[row * 32 + (tid >> 3)] = m;
    m = fmaxf(m, __shfl_xor(m, 8, 64));
    m = fmaxf(m, __shfl_xor(m, 16, 64));
    m = fmaxf(m, __shfl_xor(m, 32, 64));
    __shared__ float red[4];
    if ((tid & 63) == 0) red[tid >> 6] = m;
    __syncthreads();
    if (tid == 0)
        ebmax[row] = fmaxf(fmaxf(red[0], red[1]), fmaxf(red[2], red[3]));
}

// ---------------- stats: qn/kn per (b,h,l) ----------------
__global__ __launch_bounds__(256) void qk_stats(
    const unsigned short* __restrict__ Qh, const unsigned short* __restrict__ Kh,
    float* __restrict__ qn, float* __restrict__ kn)
{
    const int l0 = blockIdx.x * 64, h = blockIdx.y, b = blockIdx.z;
    const int tid = threadIdx.x;
    const int r = tid >> 2, p4 = (tid & 3) * 16;
    const unsigned short* q = Qh + ((long long)b * L_SEQ + l0 + r) * D_MODEL + h * DK + p4;
    const unsigned short* k = Kh + ((long long)b * L_SEQ + l0 + r) * D_MODEL + h * DK + p4;
    float sq = 0.f, sk = 0.f;
#pragma unroll
    for (int i = 0; i < 16; i++) {
        float qv = bf2f(q[i]); sq += qv * qv;
        float kv = bf2f(k[i]); sk += kv * kv;
    }
    sq += __shfl_xor(sq, 1, 64); sq += __shfl_xor(sq, 2, 64);
    sk += __shfl_xor(sk, 1, 64); sk += __shfl_xor(sk, 2, 64);
    if ((tid & 3) == 0) {
        long long idx = ((long long)(b * NUM_HEADS + h)) * L_SEQ + l0 + r;
        qn[idx] = sqrtf(sq);
        kn[idx] = sqrtf(sk);
    }
}

// ---------------- stats: per-(b,h) k-norm global + per-tile max ----------------
__global__ __launch_bounds__(256) void kstats2(
    const float* __restrict__ kn, float* __restrict__ kmax, float* __restrict__ ktmax)
{
    const long long bh = blockIdx.x;
    const float* p = kn + bh * L_SEQ;
    const int tid = threadIdx.x;
    float4 a = *(const float4*)(p + tid * 8);
    float4 c = *(const float4*)(p + tid * 8 + 4);
    float m = fmaxf(fmaxf(fmaxf(a.x, a.y), fmaxf(a.z, a.w)),
                    fmaxf(fmaxf(c.x, c.y), fmaxf(c.z, c.w)));
    m = fmaxf(m, __shfl_xor(m, 1, 64));
    m = fmaxf(m, __shfl_xor(m, 2, 64));
    m = fmaxf(m, __shfl_xor(m, 4, 64));
    if ((tid & 7) == 0) ktmax[bh * 32 + (tid >> 3)] = m;
    m = fmaxf(m, __shfl_xor(m, 8, 64));
    m = fmaxf(m, __shfl_xor(m, 16, 64));
    m = fmaxf(m, __shfl_xor(m, 32, 64));
    __shared__ float red[4];
    if ((tid & 63) == 0) red[tid >> 6] = m;
    __syncthreads();
    if (tid == 0)
        kmax[bh] = fmaxf(fmaxf(red[0], red[1]), fmaxf(red[2], red[3]));
}

// ---------------- skip mask: bit t set iff tile t provably negligible ----------------
__global__ __launch_bounds__(64) void skip_mask(
    const float* __restrict__ ebmax, const float* __restrict__ ebtmax,
    const float* __restrict__ qn, const float* __restrict__ kmax,
    const float* __restrict__ ktmax, unsigned int* __restrict__ skipm)
{
    const int l0 = blockIdx.x * 64, h = blockIdx.y, b = blockIdx.z;
    const int tid = threadIdx.x;
    const int row = l0 + tid;
    const int bh = b * NUM_HEADS + h;
    float q = qn[(long long)bh * L_SEQ + row];
    float Mh = ENERGY_SCALE * ebmax[(long long)b * L_SEQ + row] + q * kmax[bh] * 0.125f + 0.02f;
    const float* ebt = ebtmax + ((long long)b * L_SEQ + row) * 32;
    const float* ktm = ktmax + bh * 32;
    unsigned int m = 0;
    for (int t = 0; t < 32; t++) {
        float ub = ENERGY_SCALE * ebt[t] + q * ktm[t] * 0.125f;
        unsigned long long bal = __ballot(ub < Mh - 45.0f);
        if (bal == ~0ull) m |= (1u << t);
    }
    if (tid == 0) skipm[bh * 32 + blockIdx.x] = m;
}

// ---------------- MFMA attention: single sweep + provable tile skip ----------------
__global__ __launch_bounds__(256) void attn_mfma(
    const unsigned short* __restrict__ Qh, const unsigned short* __restrict__ Kh,
    const unsigned short* __restrict__ Vt, const float* __restrict__ EB,
    const float* __restrict__ ebmax, const float* __restrict__ qn,
    const float* __restrict__ kmax, const unsigned int* __restrict__ skipm,
    float* __restrict__ attn_out, unsigned short* __restrict__ CTXh)
{
    __shared__ unsigned short Ks[64 * 72];
    __shared__ unsigned short Vts[64 * 72];
    __shared__ unsigned short Ps[4 * 16 * 72];

    const int tid = threadIdx.x;
    const int lane = tid & 63, w = tid >> 6;
    const int quad = lane >> 4, col = lane & 15;
    const int l0 = blockIdx.x * 64;
    const int h = blockIdx.y, b = blockIdx.z;

    short8 aq[2];
    {
        const unsigned short* qrow = Qh + ((long long)b * L_SEQ + l0 + w * 16 + col) * D_MODEL + h * DK;
        aq[0] = *(const short8*)(qrow + quad * 8);
        aq[1] = *(const short8*)(qrow + 32 + quad * 8);
    }

    float Mhat[4];
    {
        const float km = kmax[b * NUM_HEADS + h];
#pragma unroll
        for (int reg = 0; reg < 4; reg++) {
            int row = l0 + w * 16 + quad * 4 + reg;
            float qb = qn[((long long)(b * NUM_HEADS + h)) * L_SEQ + row];
            Mhat[reg] = ENERGY_SCALE * ebmax[(long long)b * L_SEQ + row] +
                        qb * km * 0.125f + 0.02f;
        }
    }

    const unsigned int sm = skipm[(b * NUM_HEADS + h) * 32 + blockIdx.x];

    const float* ebp = EB + ((long long)b * L_SEQ + l0 + w * 16 + quad * 4) * L_SEQ + col;
    const unsigned short* kbase = Kh + ((long long)b * L_SEQ) * D_MODEL + h * DK;
    const unsigned short* vbase = Vt + ((long long)(b * NUM_HEADS + h)) * DK * L_SEQ;

    const int sr = tid >> 2, sc0 = (tid & 3) * 16;

    // ---- pass 1: rowS over active tiles only ----
    float rowSacc[4] = {0.f, 0.f, 0.f, 0.f};
    for (int t = 0; t < 32; t++) {
        if (sm & (1u << t)) continue;
        const int m0 = t * 64;
        __syncthreads();
        *(uint4*)(Ks + sr * 72 + sc0)     = *(const uint4*)(kbase + (long long)(m0 + sr) * D_MODEL + sc0);
        *(uint4*)(Ks + sr * 72 + sc0 + 8) = *(const uint4*)(kbase + (long long)(m0 + sr) * D_MODEL + sc0 + 8);
        __syncthreads();

        f32x4 acc[4];
#pragma unroll
        for (int nt = 0; nt < 4; nt++) acc[nt] = (f32x4){0.f, 0.f, 0.f, 0.f};
#pragma unroll
        for (int nt = 0; nt < 4; nt++)
#pragma unroll
            for (int kc = 0; kc < 2; kc++) {
                short8 bk = *(const short8*)(Ks + (nt * 16 + col) * 72 + quad * 8 + kc * 32);
                acc[nt] = __builtin_amdgcn_mfma_f32_16x16x32_bf16(aq[kc], bk, acc[nt], 0, 0, 0);
            }
#pragma unroll
        for (int nt = 0; nt < 4; nt++)
#pragma unroll
            for (int reg = 0; reg < 4; reg++) {
                float s = acc[nt][reg] * 0.125f + ENERGY_SCALE * ebp[(long long)reg * L_SEQ + m0 + nt * 16];
                rowSacc[reg] += __expf(s - Mhat[reg]);
            }
    }

    float invS[4];
#pragma unroll
    for (int reg = 0; reg < 4; reg++) {
        float v = rowSacc[reg];
#pragma unroll
        for (int off = 8; off > 0; off >>= 1) v += __shfl_xor(v, off, 64);
        invS[reg] = 1.f / v;
    }

    // ---- pass 2: write attn (zeros for skipped tiles), ctx = P V ----
    f32x4 ctx[4];
#pragma unroll
    for (int nt = 0; nt < 4; nt++) ctx[nt] = (f32x4){0.f, 0.f, 0.f, 0.f};

    unsigned short* Psw = Ps + w * 16 * 72;
    float* aob = attn_out + (((long long)(b * NUM_HEADS + h)) * L_SEQ + l0 + w * 16 + quad * 4) * L_SEQ + col;

    for (int t = 0; t < 32; t++) {
        const int m0 = t * 64;
        if (sm & (1u << t)) {
#pragma unroll
            for (int nt = 0; nt < 4; nt++)
#pragma unroll
                for (int reg = 0; reg < 4; reg++)
                    aob[(long long)reg * L_SEQ + m0 + nt * 16] = 0.f;
            continue;
        }
        __syncthreads();
        *(uint4*)(Ks + sr * 72 + sc0)      = *(const uint4*)(kbase + (long long)(m0 + sr) * D_MODEL + sc0);
        *(uint4*)(Ks + sr * 72 + sc0 + 8)  = *(const uint4*)(kbase + (long long)(m0 + sr) * D_MODEL + sc0 + 8);
        *(uint4*)(Vts + sr * 72 + sc0)     = *(const uint4*)(vbase + (long long)sr * L_SEQ + m0 + sc0);
        *(uint4*)(Vts + sr * 72 + sc0 + 8) = *(const uint4*)(vbase + (long long)sr * L_SEQ + m0 + sc0 + 8);
        __syncthreads();

        f32x4 acc[4];
#pragma unroll
        for (int nt = 0; nt < 4; nt++) acc[nt] = (f32x4){0.f, 0.f, 0.f, 0.f};
#pragma unroll
        for (int nt = 0; nt < 4; nt++)
#pragma unroll
            for (int kc = 0; kc < 2; kc++) {
                short8 bk = *(const short8*)(Ks + (nt * 16 + col) * 72 + quad * 8 + kc * 32);
                acc[nt] = __builtin_amdgcn_mfma_f32_16x16x32_bf16(aq[kc], bk, acc[nt], 0, 0, 0);
            }

#pragma unroll
        for (int nt = 0; nt < 4; nt++)
#pragma unroll
            for (int reg = 0; reg < 4; reg++) {
                float s = acc[nt][reg] * 0.125f + ENERGY_SCALE * ebp[(long long)reg * L_SEQ + m0 + nt * 16];
                float p = __expf(s - Mhat[reg]) * invS[reg];
                aob[(long long)reg * L_SEQ + m0 + nt * 16] = p;
                Psw[(quad * 4 + reg) * 72 + nt * 16 + col] = f2bf(p);
            }

        short8 ap[2];
#pragma unroll
        for (int kc = 0; kc < 2; kc++)
            ap[kc] = *(const short8*)(Psw + col * 72 + quad * 8 + kc * 32);
#pragma unroll
        for (int nt = 0; nt < 4; nt++)
#pragma unroll
            for (int kc = 0; kc < 2; kc++) {
                short8 bv = *(const short8*)(Vts + (nt * 16 + col) * 72 + quad * 8 + kc * 32);
                ctx[nt] = __builtin_amdgcn_mfma_f32_16x16x32_bf16(ap[kc], bv, ctx[nt], 0, 0, 0);
            }
    }

#pragma unroll
    for (int nt = 0; nt < 4; nt++)
#pragma unroll
        for (int reg = 0; reg < 4; reg++)
            CTXh[((long long)b * L_SEQ + l0 + w * 16 + quad * 4 + reg) * D_MODEL + h * DK + nt * 16 + col] =
                f2bf(ctx[nt][reg]);
}

extern "C" void kernel_launch(void* const* d_in, const int* in_sizes, int n_in,
                              void* d_out, int out_size, void* d_ws, size_t ws_size,
                              hipStream_t stream) {
    const float* x    = (const float*)d_in[0];
    const float* wq   = (const float*)d_in[1];
    const float* wk   = (const float*)d_in[2];
    const float* wv   = (const float*)d_in[3];
    const float* wo_w = (const float*)d_in[4];
    const float* wo_b = (const float*)d_in[5];
    const float* ep_w = (const float*)d_in[6];
    const float* ep_b = (const float*)d_in[7];
    const float* en_g = (const float*)d_in[8];
    const float* en_b = (const float*)d_in[9];
    const float* ln_g = (const float*)d_in[10];
    const float* ln_b = (const float*)d_in[11];

    float* out_final = (float*)d_out;
    float* attn_out  = out_final + (long long)BATCH * L_SEQ * D_MODEL;

    const long long MD = (long long)BATCH * L_SEQ * D_MODEL;   // 4,194,304
    const long long WN = (long long)D_MODEL * D_MODEL;         // 1,048,576
    const long long BH = (long long)BATCH * NUM_HEADS;

    float* EB = (float*)d_ws;                                  // [B,L,L] fp32
    float* EP = EB + (long long)BATCH * L_SEQ * L_SEQ;         // MD fp32 (also OUT)
    unsigned short* Xh   = (unsigned short*)(EP + MD);
    unsigned short* Qh   = Xh + MD;
    unsigned short* Kh   = Qh + MD;
    unsigned short* Vf   = Kh + MD;
    unsigned short* Vt   = Vf + MD;
    unsigned short* EFh  = Vt + MD;
    unsigned short* CTXh = EFh + MD;
    unsigned short* wqh  = CTXh + MD;
    unsigned short* wkh  = wqh + WN;
    unsigned short* wvh  = wkh + WN;
    unsigned short* eph  = wvh + WN;
    unsigned short* woh  = eph + WN;
    float* ebmax  = (float*)(woh + WN);                        // B*L
    float* qn     = ebmax + (long long)BATCH * L_SEQ;          // B*H*L
    float* kn     = qn + BH * L_SEQ;                           // B*H*L
    float* kmax   = kn + BH * L_SEQ;                           // B*H
    float* ktmax  = kmax + BH;                                 // B*H*32
    float* ebtmax = ktmax + BH * 32;                           // B*L*32
    unsigned int* skipm = (unsigned int*)(ebtmax + (long long)BATCH * L_SEQ * 32); // B*H*32
    float* OUT = EP;                                           // EP dead after ln

    const int M = BATCH * L_SEQ;                               // 4096
    dim3 blk(256);

    cvt6<<<dim3((unsigned)(MD / 1024), 6), blk, 0, stream>>>(
        x, wq, wk, wv, ep_w, wo_w, Xh, wqh, wkh, wvh, eph, woh,
        MD, WN, WN, WN, WN, WN);

    proj_gemm<<<dim3(D_MODEL / 128, M / 128, 4), blk, 0, stream>>>(
        Xh, wqh, wkh, wvh, eph, ep_b, Qh, Kh, Vf, EP);

    ln_rows<<<dim3(M), blk, 0, stream>>>(EP, nullptr, en_g, en_b, nullptr, EFh);

    gemm_bf16<<<dim3(L_SEQ / 128, L_SEQ / 128, BATCH), blk, 0, stream>>>(
        EFh, EFh, nullptr, EB, nullptr, L_SEQ, D_MODEL,
        (long long)L_SEQ * D_MODEL, (long long)L_SEQ * D_MODEL,
        (long long)L_SEQ * L_SEQ);

    qk_stats<<<dim3(L_SEQ / 64, NUM_HEADS, BATCH), blk, 0, stream>>>(Qh, Kh, qn, kn);
    kstats2<<<dim3((unsigned)BH), blk, 0, stream>>>(kn, kmax, ktmax);
    eb_stats<<<dim3(M), blk, 0, stream>>>(EB, ebmax, ebtmax);
    skip_mask<<<dim3(L_SEQ / 64, NUM_HEADS, BATCH), dim3(64), 0, stream>>>(
        ebmax, ebtmax, qn, kmax, ktmax, skipm);

    transpose_v<<<dim3(L_SEQ / 64, NUM_HEADS, BATCH), blk, 0, stream>>>(Vf, Vt);

    attn_mfma<<<dim3(L_SEQ / 64, NUM_HEADS, BATCH), blk, 0, stream>>>(
        Qh, Kh, Vt, EB, ebmax, qn, kmax, skipm, attn_out, CTXh);

    gemm_bf16<<<dim3(D_MODEL / 128, M / 128, 1), blk, 0, stream>>>(
        CTXh, woh, wo_b, OUT, nullptr, D_MODEL, D_MODEL, 0, 0, 0);

    ln_rows<<<dim3(M), blk, 0, stream>>>(OUT, x, ln_g, ln_b, out_final, nullptr);
}

// Round 9
// 759.335 us; speedup vs baseline: 1.4351x; 1.0320x over previous
//
#include <hip/hip_runtime.h>
#include <math.h>

#define D_MODEL 1024
#define NUM_HEADS 16
#define DK 64
#define L_SEQ 2048
#define BATCH 2
#define LN_EPS 1e-5f
#define ENERGY_SCALE 0.1f

typedef __attribute__((ext_vector_type(8))) short short8;
typedef __attribute__((ext_vector_type(4))) float f32x4;
typedef __attribute__((address_space(1))) const unsigned int gas_u32;
typedef __attribute__((address_space(3))) unsigned int las_u32;

__device__ __forceinline__ float waveReduceSum(float v) {
#pragma unroll
    for (int off = 32; off > 0; off >>= 1) v += __shfl_xor(v, off, 64);
    return v;
}

__device__ __forceinline__ unsigned short f2bf(float f) {
    unsigned int u = __float_as_uint(f);
    u += 0x7fff + ((u >> 16) & 1);          // round-to-nearest-even
    return (unsigned short)(u >> 16);
}
__device__ __forceinline__ float bf2f(unsigned short u) {
    return __uint_as_float((unsigned int)u << 16);
}

// ---------------- fp32 -> bf16 convert, 6 matrices in one launch ----------------
__global__ __launch_bounds__(256) void cvt6(
    const float* s0, const float* s1, const float* s2,
    const float* s3, const float* s4, const float* s5,
    unsigned short* d0, unsigned short* d1, unsigned short* d2,
    unsigned short* d3, unsigned short* d4, unsigned short* d5,
    long long n0, long long n1, long long n2, long long n3, long long n4, long long n5)
{
    const float* s; unsigned short* d; long long n;
    switch (blockIdx.y) {
        case 0: s = s0; d = d0; n = n0; break;
        case 1: s = s1; d = d1; n = n1; break;
        case 2: s = s2; d = d2; n = n2; break;
        case 3: s = s3; d = d3; n = n3; break;
        case 4: s = s4; d = d4; n = n4; break;
        default: s = s5; d = d5; n = n5; break;
    }
    long long i = ((long long)blockIdx.x * 256 + threadIdx.x) * 4;
    if (i >= n) return;
    float4 v = *(const float4*)(s + i);
    ushort4 o;
    o.x = f2bf(v.x); o.y = f2bf(v.y); o.z = f2bf(v.z); o.w = f2bf(v.w);
    *(ushort4*)(d + i) = o;
}

// ---------------- bf16 MFMA GEMM with global_load_lds (round-8 verified) ----------------
__global__ __launch_bounds__(256) void gemm_bf16(
    const unsigned short* __restrict__ A, const unsigned short* __restrict__ B,
    const float* __restrict__ bias, float* __restrict__ Cf, unsigned short* __restrict__ Ch,
    int N, int K, long long sA, long long sB, long long sC)
{
    A += (long long)blockIdx.z * sA;
    B += (long long)blockIdx.z * sB;
    __shared__ unsigned short As[128 * 64];
    __shared__ unsigned short Bs[128 * 64];
    const int tid = threadIdx.x;
    const int lane = tid & 63, w = tid >> 6;
    const int quad = lane >> 4, col = lane & 15;
    const int wm = w & 1, wn = w >> 1;
    const int row0 = blockIdx.y * 128, col0 = blockIdx.x * 128;

    const int lr = lane >> 3, lc = lane & 7;
    const int gcs = (lc ^ lr) * 8;

    f32x4 acc[4][4];
#pragma unroll
    for (int mt = 0; mt < 4; mt++)
#pragma unroll
        for (int nt = 0; nt < 4; nt++) acc[mt][nt] = (f32x4){0.f, 0.f, 0.f, 0.f};

    for (int k0 = 0; k0 < K; k0 += 64) {
        __syncthreads();
#pragma unroll
        for (int p = 0; p < 4; p++) {
            const int rb = w * 32 + p * 8;
            __builtin_amdgcn_global_load_lds(
                (gas_u32*)(A + (long long)(row0 + rb + lr) * K + k0 + gcs),
                (las_u32*)(As + rb * 64), 16, 0, 0);
            __builtin_amdgcn_global_load_lds(
                (gas_u32*)(B + (long long)(col0 + rb + lr) * K + k0 + gcs),
                (las_u32*)(Bs + rb * 64), 16, 0, 0);
        }
        __syncthreads();
#pragma unroll
        for (int kc = 0; kc < 2; kc++) {
            const int csw = ((quad + 4 * kc) ^ (col & 7)) * 8;
            short8 af[4], bfr[4];
#pragma unroll
            for (int mt = 0; mt < 4; mt++)
                af[mt] = *(const short8*)(As + (wm * 64 + mt * 16 + col) * 64 + csw);
#pragma unroll
            for (int nt = 0; nt < 4; nt++)
                bfr[nt] = *(const short8*)(Bs + (wn * 64 + nt * 16 + col) * 64 + csw);
#pragma unroll
            for (int mt = 0; mt < 4; mt++)
#pragma unroll
                for (int nt = 0; nt < 4; nt++)
                    acc[mt][nt] = __builtin_amdgcn_mfma_f32_16x16x32_bf16(af[mt], bfr[nt], acc[mt][nt], 0, 0, 0);
        }
    }

#pragma unroll
    for (int mt = 0; mt < 4; mt++)
#pragma unroll
        for (int nt = 0; nt < 4; nt++)
#pragma unroll
            for (int reg = 0; reg < 4; reg++) {
                long long row = row0 + wm * 64 + mt * 16 + quad * 4 + reg;
                int c = col0 + wn * 64 + nt * 16 + col;
                float v = acc[mt][nt][reg];
                if (bias) v += bias[c];
                if (Cf) Cf[blockIdx.z * sC + row * N + c] = v;
                else    Ch[blockIdx.z * sC + row * N + c] = f2bf(v);
            }
}

// ---------------- fused projections with global_load_lds (round-8 verified) ----------------
__global__ __launch_bounds__(256) void proj_gemm(
    const unsigned short* __restrict__ Xh,
    const unsigned short* __restrict__ wqh, const unsigned short* __restrict__ wkh,
    const unsigned short* __restrict__ wvh, const unsigned short* __restrict__ eph,
    const float* __restrict__ ep_b,
    unsigned short* __restrict__ Qh, unsigned short* __restrict__ Kh,
    unsigned short* __restrict__ Vf, float* __restrict__ EP)
{
    const unsigned short* B;
    switch (blockIdx.z) {
        case 0: B = wqh; break;
        case 1: B = wkh; break;
        case 2: B = wvh; break;
        default: B = eph; break;
    }
    __shared__ unsigned short As[128 * 64];
    __shared__ unsigned short Bs[128 * 64];
    const int tid = threadIdx.x;
    const int lane = tid & 63, w = tid >> 6;
    const int quad = lane >> 4, col = lane & 15;
    const int wm = w & 1, wn = w >> 1;
    const int row0 = blockIdx.y * 128, col0 = blockIdx.x * 128;
    const int K = D_MODEL, N = D_MODEL;

    const int lr = lane >> 3, lc = lane & 7;
    const int gcs = (lc ^ lr) * 8;

    f32x4 acc[4][4];
#pragma unroll
    for (int mt = 0; mt < 4; mt++)
#pragma unroll
        for (int nt = 0; nt < 4; nt++) acc[mt][nt] = (f32x4){0.f, 0.f, 0.f, 0.f};

    for (int k0 = 0; k0 < K; k0 += 64) {
        __syncthreads();
#pragma unroll
        for (int p = 0; p < 4; p++) {
            const int rb = w * 32 + p * 8;
            __builtin_amdgcn_global_load_lds(
                (gas_u32*)(Xh + (long long)(row0 + rb + lr) * K + k0 + gcs),
                (las_u32*)(As + rb * 64), 16, 0, 0);
            __builtin_amdgcn_global_load_lds(
                (gas_u32*)(B + (long long)(col0 + rb + lr) * K + k0 + gcs),
                (las_u32*)(Bs + rb * 64), 16, 0, 0);
        }
        __syncthreads();
#pragma unroll
        for (int kc = 0; kc < 2; kc++) {
            const int csw = ((quad + 4 * kc) ^ (col & 7)) * 8;
            short8 af[4], bfr[4];
#pragma unroll
            for (int mt = 0; mt < 4; mt++)
                af[mt] = *(const short8*)(As + (wm * 64 + mt * 16 + col) * 64 + csw);
#pragma unroll
            for (int nt = 0; nt < 4; nt++)
                bfr[nt] = *(const short8*)(Bs + (wn * 64 + nt * 16 + col) * 64 + csw);
#pragma unroll
            for (int mt = 0; mt < 4; mt++)
#pragma unroll
                for (int nt = 0; nt < 4; nt++)
                    acc[mt][nt] = __builtin_amdgcn_mfma_f32_16x16x32_bf16(af[mt], bfr[nt], acc[mt][nt], 0, 0, 0);
        }
    }

    unsigned short* Hout = (blockIdx.z == 0) ? Qh : (blockIdx.z == 1) ? Kh : Vf;
#pragma unroll
    for (int mt = 0; mt < 4; mt++)
#pragma unroll
        for (int nt = 0; nt < 4; nt++)
#pragma unroll
            for (int reg = 0; reg < 4; reg++) {
                long long row = row0 + wm * 64 + mt * 16 + quad * 4 + reg;
                int c = col0 + wn * 64 + nt * 16 + col;
                float v = acc[mt][nt][reg];
                if (blockIdx.z == 3) EP[row * N + c] = v + ep_b[c];
                else                 Hout[row * N + c] = f2bf(v);
            }
}

// ---------------- LayerNorm rows ----------------
__global__ __launch_bounds__(256) void ln_rows(
    const float* __restrict__ in, const float* __restrict__ res,
    const float* __restrict__ g, const float* __restrict__ bta,
    float* __restrict__ outf, unsigned short* __restrict__ outh)
{
    const long long row = blockIdx.x;
    const float* ip = in + row * D_MODEL;
    const float* rp = res ? res + row * D_MODEL : nullptr;
    const int tid = threadIdx.x;
    float vals[4];
    float s = 0.f, ss = 0.f;
#pragma unroll
    for (int j = 0; j < 4; j++) {
        int idx = tid + j * 256;
        float v = ip[idx];
        if (rp) v += rp[idx];
        vals[j] = v; s += v; ss += v * v;
    }
    __shared__ float sred[4], ssred[4];
    s = waveReduceSum(s); ss = waveReduceSum(ss);
    int wave = tid >> 6, lane = tid & 63;
    if (lane == 0) { sred[wave] = s; ssred[wave] = ss; }
    __syncthreads();
    float ts = sred[0] + sred[1] + sred[2] + sred[3];
    float tss = ssred[0] + ssred[1] + ssred[2] + ssred[3];
    float mu = ts * (1.f / D_MODEL);
    float var = tss * (1.f / D_MODEL) - mu * mu;
    float rs = rsqrtf(var + LN_EPS);
#pragma unroll
    for (int j = 0; j < 4; j++) {
        int idx = tid + j * 256;
        float o = (vals[j] - mu) * rs * g[idx] + bta[idx];
        if (outf) outf[row * D_MODEL + idx] = o;
        else      outh[row * D_MODEL + idx] = f2bf(o);
    }
}

// ---------------- V transpose ----------------
__global__ __launch_bounds__(256) void transpose_v(
    const unsigned short* __restrict__ V, unsigned short* __restrict__ Vt)
{
    const int m0 = blockIdx.x * 64, h = blockIdx.y, b = blockIdx.z;
    __shared__ unsigned int t[64][65];
    const int tid = threadIdx.x;
    {
        int r = tid >> 4, c4 = (tid & 15) * 4;
#pragma unroll
        for (int i = 0; i < 4; i++) {
            int row = r + i * 16;
            ushort4 v = *(const ushort4*)(V + ((long long)b * L_SEQ + m0 + row) * D_MODEL + h * DK + c4);
            t[row][c4] = v.x; t[row][c4 + 1] = v.y; t[row][c4 + 2] = v.z; t[row][c4 + 3] = v.w;
        }
    }
    __syncthreads();
    const int lane = tid & 63, wv = tid >> 6;
#pragma unroll
    for (int i = 0; i < 16; i++) {
        int d = wv * 16 + i;
        Vt[(((long long)(b * NUM_HEADS + h)) * DK + d) * L_SEQ + m0 + lane] = (unsigned short)t[lane][d];
    }
}

// ---------------- stats: EB row max + per-64-tile max, one pass ----------------
__global__ __launch_bounds__(256) void eb_stats(
    const float* __restrict__ EB, float* __restrict__ ebmax, float* __restrict__ ebtmax)
{
    const long long row = blockIdx.x;
    const float* p = EB + row * L_SEQ;
    const int tid = threadIdx.x;
    float4 a = *(const float4*)(p + tid * 8);
    float4 c = *(const float4*)(p + tid * 8 + 4);
    float m = fmaxf(fmaxf(fmaxf(a.x, a.y), fmaxf(a.z, a.w)),
                    fmaxf(fmaxf(c.x, c.y), fmaxf(c.z, c.w)));
    m = fmaxf(m, __shfl_xor(m, 1, 64));
    m = fmaxf(m, __shfl_xor(m, 2, 64));
    m = fmaxf(m, __shfl_xor(m, 4, 64));
    if ((tid & 7) == 0) ebtmax[row * 32 + (tid >> 3)] = m;
    m = fmaxf(m, __shfl_xor(m, 8, 64));
    m = fmaxf(m, __shfl_xor(m, 16, 64));
    m = fmaxf(m, __shfl_xor(m, 32, 64));
    __shared__ float red[4];
    if ((tid & 63) == 0) red[tid >> 6] = m;
    __syncthreads();
    if (tid == 0)
        ebmax[row] = fmaxf(fmaxf(red[0], red[1]), fmaxf(red[2], red[3]));
}

// ---------------- stats: qn/kn per (b,h,l) ----------------
__global__ __launch_bounds__(256) void qk_stats(
    const unsigned short* __restrict__ Qh, const unsigned short* __restrict__ Kh,
    float* __restrict__ qn, float* __restrict__ kn)
{
    const int l0 = blockIdx.x * 64, h = blockIdx.y, b = blockIdx.z;
    const int tid = threadIdx.x;
    const int r = tid >> 2, p4 = (tid & 3) * 16;
    const unsigned short* q = Qh + ((long long)b * L_SEQ + l0 + r) * D_MODEL + h * DK + p4;
    const unsigned short* k = Kh + ((long long)b * L_SEQ + l0 + r) * D_MODEL + h * DK + p4;
    float sq = 0.f, sk = 0.f;
#pragma unroll
    for (int i = 0; i < 16; i++) {
        float qv = bf2f(q[i]); sq += qv * qv;
        float kv = bf2f(k[i]); sk += kv * kv;
    }
    sq += __shfl_xor(sq, 1, 64); sq += __shfl_xor(sq, 2, 64);
    sk += __shfl_xor(sk, 1, 64); sk += __shfl_xor(sk, 2, 64);
    if ((tid & 3) == 0) {
        long long idx = ((long long)(b * NUM_HEADS + h)) * L_SEQ + l0 + r;
        qn[idx] = sqrtf(sq);
        kn[idx] = sqrtf(sk);
    }
}

// ---------------- stats: per-(b,h) k-norm global + per-tile max ----------------
__global__ __launch_bounds__(256) void kstats2(
    const float* __restrict__ kn, float* __restrict__ kmax, float* __restrict__ ktmax)
{
    const long long bh = blockIdx.x;
    const float* p = kn + bh * L_SEQ;
    const int tid = threadIdx.x;
    float4 a = *(const float4*)(p + tid * 8);
    float4 c = *(const float4*)(p + tid * 8 + 4);
    float m = fmaxf(fmaxf(fmaxf(a.x, a.y), fmaxf(a.z, a.w)),
                    fmaxf(fmaxf(c.x, c.y), fmaxf(c.z, c.w)));
    m = fmaxf(m, __shfl_xor(m, 1, 64));
    m = fmaxf(m, __shfl_xor(m, 2, 64));
    m = fmaxf(m, __shfl_xor(m, 4, 64));
    if ((tid & 7) == 0) ktmax[bh * 32 + (tid >> 3)] = m;
    m = fmaxf(m, __shfl_xor(m, 8, 64));
    m = fmaxf(m, __shfl_xor(m, 16, 64));
    m = fmaxf(m, __shfl_xor(m, 32, 64));
    __shared__ float red[4];
    if ((tid & 63) == 0) red[tid >> 6] = m;
    __syncthreads();
    if (tid == 0)
        kmax[bh] = fmaxf(fmaxf(red[0], red[1]), fmaxf(red[2], red[3]));
}

// ---------------- skip mask ----------------
__global__ __launch_bounds__(64) void skip_mask(
    const float* __restrict__ ebmax, const float* __restrict__ ebtmax,
    const float* __restrict__ qn, const float* __restrict__ kmax,
    const float* __restrict__ ktmax, unsigned int* __restrict__ skipm)
{
    const int l0 = blockIdx.x * 64, h = blockIdx.y, b = blockIdx.z;
    const int tid = threadIdx.x;
    const int row = l0 + tid;
    const int bh = b * NUM_HEADS + h;
    float q = qn[(long long)bh * L_SEQ + row];
    float Mh = ENERGY_SCALE * ebmax[(long long)b * L_SEQ + row] + q * kmax[bh] * 0.125f + 0.02f;
    const float* ebt = ebtmax + ((long long)b * L_SEQ + row) * 32;
    const float* ktm = ktmax + bh * 32;
    unsigned int m = 0;
    for (int t = 0; t < 32; t++) {
        float ub = ENERGY_SCALE * ebt[t] + q * ktm[t] * 0.125f;
        unsigned long long bal = __ballot(ub < Mh - 45.0f);
        if (bal == ~0ull) m |= (1u << t);
    }
    if (tid == 0) skipm[bh * 32 + blockIdx.x] = m;
}

// ---------------- MFMA attention: up-front coalesced zero-fill + active-only passes ----------------
__global__ __launch_bounds__(256) void attn_mfma(
    const unsigned short* __restrict__ Qh, const unsigned short* __restrict__ Kh,
    const unsigned short* __restrict__ Vt, const float* __restrict__ EB,
    const float* __restrict__ ebmax, const float* __restrict__ qn,
    const float* __restrict__ kmax, const unsigned int* __restrict__ skipm,
    float* __restrict__ attn_out, unsigned short* __restrict__ CTXh)
{
    __shared__ unsigned short Ks[64 * 72];
    __shared__ unsigned short Vts[64 * 72];
    __shared__ unsigned short Ps[4 * 16 * 72];

    const int tid = threadIdx.x;
    const int lane = tid & 63, w = tid >> 6;
    const int quad = lane >> 4, col = lane & 15;
    const int l0 = blockIdx.x * 64;
    const int h = blockIdx.y, b = blockIdx.z;

    const unsigned int sm = skipm[(b * NUM_HEADS + h) * 32 + blockIdx.x];

    // ---- phase 0: coalesced float4 zero-fill for skipped tiles (fire-and-forget;
    //      no dependent reads, so these stores drain behind phase 1/2 compute) ----
    {
        float* zbase = attn_out + (((long long)(b * NUM_HEADS + h)) * L_SEQ + l0) * L_SEQ;
        const int zc = (tid & 15) * 4;          // 16 lanes cover one row's 64 cols
        const int zr = tid >> 4;                // 16 rows per instruction across block
        const float4 zv = {0.f, 0.f, 0.f, 0.f};
        for (int t = 0; t < 32; t++) {
            if (!(sm & (1u << t))) continue;
            float* tb = zbase + t * 64 + zc;
#pragma unroll
            for (int rr = 0; rr < 4; rr++)
                *(float4*)(tb + (long long)(rr * 16 + zr) * L_SEQ) = zv;
        }
    }

    short8 aq[2];
    {
        const unsigned short* qrow = Qh + ((long long)b * L_SEQ + l0 + w * 16 + col) * D_MODEL + h * DK;
        aq[0] = *(const short8*)(qrow + quad * 8);
        aq[1] = *(const short8*)(qrow + 32 + quad * 8);
    }

    float Mhat[4];
    {
        const float km = kmax[b * NUM_HEADS + h];
#pragma unroll
        for (int reg = 0; reg < 4; reg++) {
            int row = l0 + w * 16 + quad * 4 + reg;
            float qb = qn[((long long)(b * NUM_HEADS + h)) * L_SEQ + row];
            Mhat[reg] = ENERGY_SCALE * ebmax[(long long)b * L_SEQ + row] +
                        qb * km * 0.125f + 0.02f;
        }
    }

    const float* ebp = EB + ((long long)b * L_SEQ + l0 + w * 16 + quad * 4) * L_SEQ + col;
    const unsigned short* kbase = Kh + ((long long)b * L_SEQ) * D_MODEL + h * DK;
    const unsigned short* vbase = Vt + ((long long)(b * NUM_HEADS + h)) * DK * L_SEQ;

    const int sr = tid >> 2, sc0 = (tid & 3) * 16;

    // ---- pass 1: rowS over active tiles only ----
    float rowSacc[4] = {0.f, 0.f, 0.f, 0.f};
    for (int t = 0; t < 32; t++) {
        if (sm & (1u << t)) continue;
        const int m0 = t * 64;
        __syncthreads();
        *(uint4*)(Ks + sr * 72 + sc0)     = *(const uint4*)(kbase + (long long)(m0 + sr) * D_MODEL + sc0);
        *(uint4*)(Ks + sr * 72 + sc0 + 8) = *(const uint4*)(kbase + (long long)(m0 + sr) * D_MODEL + sc0 + 8);
        __syncthreads();

        f32x4 acc[4];
#pragma unroll
        for (int nt = 0; nt < 4; nt++) acc[nt] = (f32x4){0.f, 0.f, 0.f, 0.f};
#pragma unroll
        for (int nt = 0; nt < 4; nt++)
#pragma unroll
            for (int kc = 0; kc < 2; kc++) {
                short8 bk = *(const short8*)(Ks + (nt * 16 + col) * 72 + quad * 8 + kc * 32);
                acc[nt] = __builtin_amdgcn_mfma_f32_16x16x32_bf16(aq[kc], bk, acc[nt], 0, 0, 0);
            }
#pragma unroll
        for (int nt = 0; nt < 4; nt++)
#pragma unroll
            for (int reg = 0; reg < 4; reg++) {
                float s = acc[nt][reg] * 0.125f + ENERGY_SCALE * ebp[(long long)reg * L_SEQ + m0 + nt * 16];
                rowSacc[reg] += __expf(s - Mhat[reg]);
            }
    }

    float invS[4];
#pragma unroll
    for (int reg = 0; reg < 4; reg++) {
        float v = rowSacc[reg];
#pragma unroll
        for (int off = 8; off > 0; off >>= 1) v += __shfl_xor(v, off, 64);
        invS[reg] = 1.f / v;
    }

    // ---- pass 2: active tiles only — write attn p's, ctx = P V ----
    f32x4 ctx[4];
#pragma unroll
    for (int nt = 0; nt < 4; nt++) ctx[nt] = (f32x4){0.f, 0.f, 0.f, 0.f};

    unsigned short* Psw = Ps + w * 16 * 72;
    float* aob = attn_out + (((long long)(b * NUM_HEADS + h)) * L_SEQ + l0 + w * 16 + quad * 4) * L_SEQ + col;

    for (int t = 0; t < 32; t++) {
        if (sm & (1u << t)) continue;
        const int m0 = t * 64;
        __syncthreads();
        *(uint4*)(Ks + sr * 72 + sc0)      = *(const uint4*)(kbase + (long long)(m0 + sr) * D_MODEL + sc0);
        *(uint4*)(Ks + sr * 72 + sc0 + 8)  = *(const uint4*)(kbase + (long long)(m0 + sr) * D_MODEL + sc0 + 8);
        *(uint4*)(Vts + sr * 72 + sc0)     = *(const uint4*)(vbase + (long long)sr * L_SEQ + m0 + sc0);
        *(uint4*)(Vts + sr * 72 + sc0 + 8) = *(const uint4*)(vbase + (long long)sr * L_SEQ + m0 + sc0 + 8);
        __syncthreads();

        f32x4 acc[4];
#pragma unroll
        for (int nt = 0; nt < 4; nt++) acc[nt] = (f32x4){0.f, 0.f, 0.f, 0.f};
#pragma unroll
        for (int nt = 0; nt < 4; nt++)
#pragma unroll
            for (int kc = 0; kc < 2; kc++) {
                short8 bk = *(const short8*)(Ks + (nt * 16 + col) * 72 + quad * 8 + kc * 32);
                acc[nt] = __builtin_amdgcn_mfma_f32_16x16x32_bf16(aq[kc], bk, acc[nt], 0, 0, 0);
            }

#pragma unroll
        for (int nt = 0; nt < 4; nt++)
#pragma unroll
            for (int reg = 0; reg < 4; reg++) {
                float s = acc[nt][reg] * 0.125f + ENERGY_SCALE * ebp[(long long)reg * L_SEQ + m0 + nt * 16];
                float p = __expf(s - Mhat[reg]) * invS[reg];
                aob[(long long)reg * L_SEQ + m0 + nt * 16] = p;
                Psw[(quad * 4 + reg) * 72 + nt * 16 + col] = f2bf(p);
            }

        short8 ap[2];
#pragma unroll
        for (int kc = 0; kc < 2; kc++)
            ap[kc] = *(const short8*)(Psw + col * 72 + quad * 8 + kc * 32);
#pragma unroll
        for (int nt = 0; nt < 4; nt++)
#pragma unroll
            for (int kc = 0; kc < 2; kc++) {
                short8 bv = *(const short8*)(Vts + (nt * 16 + col) * 72 + quad * 8 + kc * 32);
                ctx[nt] = __builtin_amdgcn_mfma_f32_16x16x32_bf16(ap[kc], bv, ctx[nt], 0, 0, 0);
            }
    }

#pragma unroll
    for (int nt = 0; nt < 4; nt++)
#pragma unroll
        for (int reg = 0; reg < 4; reg++)
            CTXh[((long long)b * L_SEQ + l0 + w * 16 + quad * 4 + reg) * D_MODEL + h * DK + nt * 16 + col] =
                f2bf(ctx[nt][reg]);
}

extern "C" void kernel_launch(void* const* d_in, const int* in_sizes, int n_in,
                              void* d_out, int out_size, void* d_ws, size_t ws_size,
                              hipStream_t stream) {
    const float* x    = (const float*)d_in[0];
    const float* wq   = (const float*)d_in[1];
    const float* wk   = (const float*)d_in[2];
    const float* wv   = (const float*)d_in[3];
    const float* wo_w = (const float*)d_in[4];
    const float* wo_b = (const float*)d_in[5];
    const float* ep_w = (const float*)d_in[6];
    const float* ep_b = (const float*)d_in[7];
    const float* en_g = (const float*)d_in[8];
    const float* en_b = (const float*)d_in[9];
    const float* ln_g = (const float*)d_in[10];
    const float* ln_b = (const float*)d_in[11];

    float* out_final = (float*)d_out;
    float* attn_out  = out_final + (long long)BATCH * L_SEQ * D_MODEL;

    const long long MD = (long long)BATCH * L_SEQ * D_MODEL;   // 4,194,304
    const long long WN = (long long)D_MODEL * D_MODEL;         // 1,048,576
    const long long BH = (long long)BATCH * NUM_HEADS;

    float* EB = (float*)d_ws;                                  // [B,L,L] fp32
    float* EP = EB + (long long)BATCH * L_SEQ * L_SEQ;         // MD fp32 (also OUT)
    unsigned short* Xh   = (unsigned short*)(EP + MD);
    unsigned short* Qh   = Xh + MD;
    unsigned short* Kh   = Qh + MD;
    unsigned short* Vf   = Kh + MD;
    unsigned short* Vt   = Vf + MD;
    unsigned short* EFh  = Vt + MD;
    unsigned short* CTXh = EFh + MD;
    unsigned short* wqh  = CTXh + MD;
    unsigned short* wkh  = wqh + WN;
    unsigned short* wvh  = wkh + WN;
    unsigned short* eph  = wvh + WN;
    unsigned short* woh  = eph + WN;
    float* ebmax  = (float*)(woh + WN);                        // B*L
    float* qn     = ebmax + (long long)BATCH * L_SEQ;          // B*H*L
    float* kn     = qn + BH * L_SEQ;                           // B*H*L
    float* kmax   = kn + BH * L_SEQ;                           // B*H
    float* ktmax  = kmax + BH;                                 // B*H*32
    float* ebtmax = ktmax + BH * 32;                           // B*L*32
    unsigned int* skipm = (unsigned int*)(ebtmax + (long long)BATCH * L_SEQ * 32); // B*H*32
    float* OUT = EP;                                           // EP dead after ln

    const int M = BATCH * L_SEQ;                               // 4096
    dim3 blk(256);

    cvt6<<<dim3((unsigned)(MD / 1024), 6), blk, 0, stream>>>(
        x, wq, wk, wv, ep_w, wo_w, Xh, wqh, wkh, wvh, eph, woh,
        MD, WN, WN, WN, WN, WN);

    proj_gemm<<<dim3(D_MODEL / 128, M / 128, 4), blk, 0, stream>>>(
        Xh, wqh, wkh, wvh, eph, ep_b, Qh, Kh, Vf, EP);

    ln_rows<<<dim3(M), blk, 0, stream>>>(EP, nullptr, en_g, en_b, nullptr, EFh);

    gemm_bf16<<<dim3(L_SEQ / 128, L_SEQ / 128, BATCH), blk, 0, stream>>>(
        EFh, EFh, nullptr, EB, nullptr, L_SEQ, D_MODEL,
        (long long)L_SEQ * D_MODEL, (long long)L_SEQ * D_MODEL,
        (long long)L_SEQ * L_SEQ);

    qk_stats<<<dim3(L_SEQ / 64, NUM_HEADS, BATCH), blk, 0, stream>>>(Qh, Kh, qn, kn);
    kstats2<<<dim3((unsigned)BH), blk, 0, stream>>>(kn, kmax, ktmax);
    eb_stats<<<dim3(M), blk, 0, stream>>>(EB, ebmax, ebtmax);
    skip_mask<<<dim3(L_SEQ / 64, NUM_HEADS, BATCH), dim3(64), 0, stream>>>(
        ebmax, ebtmax, qn, kmax, ktmax, skipm);

    transpose_v<<<dim3(L_SEQ / 64, NUM_HEADS, BATCH), blk, 0, stream>>>(Vf, Vt);

    attn_mfma<<<dim3(L_SEQ / 64, NUM_HEADS, BATCH), blk, 0, stream>>>(
        Qh, Kh, Vt, EB, ebmax, qn, kmax, skipm, attn_out, CTXh);

    gemm_bf16<<<dim3(D_MODEL / 128, M / 128, 1), blk, 0, stream>>>(
        CTXh, woh, wo_b, OUT, nullptr, D_MODEL, D_MODEL, 0, 0, 0);

    ln_rows<<<dim3(M), blk, 0, stream>>>(OUT, x, ln_g, ln_b, out_final, nullptr);
}